// Round 7
// baseline (973.852 us; speedup 1.0000x reference)
//
#include <hip/hip_runtime.h>
#include <cstdint>

// Problem dims
#define DB   8
#define DL   4096
#define DD   768
#define DDI  1536
#define DN   64
#define DH   24
#define DP   64
#define DCD  1664
#define DIPD 3224
#define BL   (DB*DL)      // 32768 tokens
#define NCH  64           // chunks (L/64)
#define ZLD  3200         // zx row stride (z 1536 | xBC 1664)

typedef __attribute__((ext_vector_type(8))) short bf16x8;
typedef __attribute__((ext_vector_type(4))) float f32x4;

__device__ __forceinline__ unsigned short f2bf(float f){
  unsigned u = __float_as_uint(f);
  u += 0x7FFFu + ((u >> 16) & 1u);
  return (unsigned short)(u >> 16);
}
__device__ __forceinline__ float bf2f(unsigned short s){
  return __uint_as_float(((unsigned)s) << 16);
}
__device__ __forceinline__ unsigned pack2(unsigned short a, unsigned short b){
  return (unsigned)a | ((unsigned)b << 16);
}
__device__ __forceinline__ void pack16(const unsigned short* ov, uint4& u0, uint4& u1){
  u0.x = pack2(ov[0],ov[1]);  u0.y = pack2(ov[2],ov[3]);
  u0.z = pack2(ov[4],ov[5]);  u0.w = pack2(ov[6],ov[7]);
  u1.x = pack2(ov[8],ov[9]);  u1.y = pack2(ov[10],ov[11]);
  u1.z = pack2(ov[12],ov[13]); u1.w = pack2(ov[14],ov[15]);
}
__device__ __forceinline__ void async16(void* lds, const void* g){
  __builtin_amdgcn_global_load_lds((const __attribute__((address_space(1))) unsigned*)g,
                                   (__attribute__((address_space(3))) unsigned*)lds, 16, 0, 0);
}
__device__ __forceinline__ float softplusf(float v){
  return v > 15.f ? v : log1pf(expf(v));
}
__device__ __forceinline__ float siluf(float v){
  return v / (1.f + expf(-v));
}

// ---------------- K0: fp32 -> bf16 weight conversion (Win, Wout) ----------------
__global__ void cvt_kernel(const float* __restrict__ win, const float* __restrict__ wout,
                           unsigned short* __restrict__ winb, unsigned short* __restrict__ woutb){
  int i = blockIdx.x*256 + threadIdx.x;
  const int WN = (DIPD*DD)/4;   // 619008
  const int ON = (DD*DDI)/4;    // 294912
  if (i < WN){
    float4 v = ((const float4*)win)[i];
    uint2 o; o.x = pack2(f2bf(v.x), f2bf(v.y)); o.y = pack2(f2bf(v.z), f2bf(v.w));
    ((uint2*)winb)[i] = o;
  } else if (i < WN+ON){
    int j = i - WN;
    float4 v = ((const float4*)wout)[j];
    uint2 o; o.x = pack2(f2bf(v.x), f2bf(v.y)); o.y = pack2(f2bf(v.z), f2bf(v.w));
    ((uint2*)woutb)[j] = o;
  }
}

// ---------------- K1: LayerNorm -> xn (bf16) ----------------
__global__ void ln_kernel(const float* __restrict__ x, const float* __restrict__ w,
                          const float* __restrict__ bb, unsigned short* __restrict__ xn){
  int row = blockIdx.x; int tid = threadIdx.x;
  const float* xr = x + (size_t)row*DD;
  float v0=xr[tid], v1=xr[tid+256], v2=xr[tid+512];
  float s = v0+v1+v2;
  float s2 = v0*v0+v1*v1+v2*v2;
  for (int off=32; off>0; off>>=1){ s += __shfl_down(s, off); s2 += __shfl_down(s2, off); }
  __shared__ float red[10];
  int wv = tid>>6;
  if ((tid&63)==0){ red[wv]=s; red[4+wv]=s2; }
  __syncthreads();
  if (tid==0){
    float a=red[0]+red[1]+red[2]+red[3];
    float c=red[4]+red[5]+red[6]+red[7];
    red[8]=a*(1.f/768.f); red[9]=c*(1.f/768.f);
  }
  __syncthreads();
  float mu = red[8];
  float inv = rsqrtf(red[9]-mu*mu + 1e-5f);
  unsigned short* o = xn + (size_t)row*DD;
  o[tid]     = f2bf((v0-mu)*inv*w[tid]     + bb[tid]);
  o[tid+256] = f2bf((v1-mu)*inv*w[tid+256] + bb[tid+256]);
  o[tid+512] = f2bf((v2-mu)*inv*w[tid+512] + bb[tid+512]);
}

// ---------------- K2: bf16 MFMA GEMM (128x128, BK=32, dbuf, conflict-free swizzle) ----------------
// Settled structure (rounds 1-6): 2-phase latency-bound ceiling ~660 TF at this shape; all
// counters <55%, six structural levers null. Swizzle kept (0 bank conflicts, bit-identical).
template<int MODE>
__launch_bounds__(256,4)
__global__ void gemm_kernel(const unsigned short* __restrict__ A,
                            const unsigned short* __restrict__ Bw,
                            int K, int lda, int Brows, int nbn,
                            unsigned short* __restrict__ zx, float* __restrict__ dtbuf,
                            const float* __restrict__ dt_bias,
                            const float* __restrict__ xres, float* __restrict__ outp)
{
  __shared__ __align__(16) unsigned short As[2*128*32];   // 16 KiB x2
  __shared__ __align__(16) unsigned short Bs[2*128*32];
  int tid = threadIdx.x; int lane = tid&63; int wv = tid>>6;
  int nwg  = gridDim.x;
  int orig = blockIdx.x;
  int q    = nwg >> 3;
  int wgid = (orig & 7)*q + (orig >> 3);
  int bm = wgid / nbn, bn = wgid % nbn;

  const int gc = ((lane&3) ^ ((lane>>3)&3)) * 8;
  const unsigned short* ap0 = A + (size_t)(bm*128 + wv*32 + (lane>>2))*lda + gc;
  const unsigned short* ap1 = ap0 + (size_t)16*lda;
  int rb0 = bn*128 + wv*32 + (lane>>2);      if (rb0 > Brows-1) rb0 = Brows-1;
  int rb1 = bn*128 + wv*32 + 16 + (lane>>2); if (rb1 > Brows-1) rb1 = Brows-1;
  const unsigned short* bp0 = Bw + (size_t)rb0*K + gc;
  const unsigned short* bp1 = Bw + (size_t)rb1*K + gc;
  unsigned short* la0 = &As[(wv*2)*512]; unsigned short* la1 = la0 + 512;
  unsigned short* lb0 = &Bs[(wv*2)*512]; unsigned short* lb1 = lb0 + 512;
  f32x4 acc[4][4];
  #pragma unroll
  for (int i=0;i<4;i++)
    #pragma unroll
    for (int j=0;j<4;j++) acc[i][j] = (f32x4){0.f,0.f,0.f,0.f};
  int mb = (wv&1)*64 + (lane&15);
  int nb = (wv>>1)*64 + (lane&15);
  const int cswz = ((lane>>4) ^ ((lane>>1)&3)) * 8;

  async16(la0, ap0); async16(la1, ap1);
  async16(lb0, bp0); async16(lb1, bp1);
  ap0 += 32; ap1 += 32; bp0 += 32; bp1 += 32;
  __syncthreads();

  int cur = 0;
  for (int k0=0; k0<K; k0+=32){
    if (k0 + 32 < K){
      int nxt = (cur^1)*4096;
      async16(la0 + nxt, ap0); async16(la1 + nxt, ap1);
      async16(lb0 + nxt, bp0); async16(lb1 + nxt, bp1);
      ap0 += 32; ap1 += 32; bp0 += 32; bp1 += 32;
    }
    const unsigned short* Ab = &As[cur*4096];
    const unsigned short* Bb = &Bs[cur*4096];
    bf16x8 af[4], bfr[4];
    #pragma unroll
    for (int i=0;i<4;i++) af[i]  = *(const bf16x8*)&Ab[(mb+i*16)*32 + cswz];
    #pragma unroll
    for (int j=0;j<4;j++) bfr[j] = *(const bf16x8*)&Bb[(nb+j*16)*32 + cswz];
    #pragma unroll
    for (int i=0;i<4;i++)
      #pragma unroll
      for (int j=0;j<4;j++)
        acc[i][j] = __builtin_amdgcn_mfma_f32_16x16x32_bf16(af[i], bfr[j], acc[i][j], 0, 0, 0);
    __syncthreads();
    cur ^= 1;
  }

  int mrow0 = bm*128 + (wv&1)*64 + (lane>>4)*4;
  int ncol0 = bn*128 + (wv>>1)*64 + (lane&15);
  #pragma unroll
  for (int i=0;i<4;i++){
    #pragma unroll
    for (int j=0;j<4;j++){
      int col = ncol0 + j*16;
      #pragma unroll
      for (int r=0;r<4;r++){
        int row = mrow0 + i*16 + r;
        float v = acc[i][j][r];
        if (MODE == 1){
          if (bn < 25){
            zx[(size_t)row*ZLD + col] = f2bf(v);
          } else {
            int cc = col - 3200;
            if (cc >= 0 && cc < DH) dtbuf[(size_t)row*DH + cc] = softplusf(v + dt_bias[cc]);
          }
        } else {
          float xr = __builtin_nontemporal_load(&xres[(size_t)row*DD + col]);
          __builtin_nontemporal_store(v + xr, &outp[(size_t)row*DD + col]);
        }
      }
    }
  }
}

// ---------------- K3: depthwise causal conv K=4 + bias + silu ----------------
// bx<24 -> xsT[b][h=bx][chunk][p][t]; bx==24 -> Bn (b,l,n) + BT (b,chunk,n,t); bx==25 -> Cn (b,l,n)
__global__ void conv_kernel(const unsigned short* __restrict__ zx,
                            const float* __restrict__ cw, const float* __restrict__ cb,
                            unsigned short* __restrict__ xsT, unsigned short* __restrict__ Bn,
                            unsigned short* __restrict__ Cn, unsigned short* __restrict__ BT)
{
  int bx = blockIdx.x, by = blockIdx.y, b = blockIdx.z;
  int tid = threadIdx.x;
  __shared__ __align__(16) unsigned short in_s[67*64];
  int l0 = by*64;
  for (int idx = tid; idx < 67*8; idx += 256){
    int r = idx >> 3, c8 = idx & 7;
    int l = l0 - 3 + r;
    uint4 v = make_uint4(0u,0u,0u,0u);
    if (l >= 0) v = *(const uint4*)&zx[(size_t)(b*DL + l)*ZLD + 1536 + bx*64 + c8*8];
    *(uint4*)&in_s[r*64 + c8*8] = v;
  }
  __syncthreads();
  int c = tid & 63, li = tid >> 6;
  int chn = bx*64 + c;
  float w0=cw[chn*4+0], w1=cw[chn*4+1], w2=cw[chn*4+2], w3=cw[chn*4+3];
  float bias = cb[chn];
  unsigned short ov[16];
  #pragma unroll
  for (int q=0;q<16;q++){
    int t = li*16 + q;
    float a = bias
      + w0*bf2f(in_s[(t+0)*64 + c])
      + w1*bf2f(in_s[(t+1)*64 + c])
      + w2*bf2f(in_s[(t+2)*64 + c])
      + w3*bf2f(in_s[(t+3)*64 + c]);
    ov[q] = f2bf(siluf(a));
  }
  if (bx < 24){
    size_t base = ((((size_t)(b*DH + bx))*64 + by)*64 + c)*64 + li*16;
    uint4 u0,u1; pack16(ov,u0,u1);
    *(uint4*)&xsT[base]   = u0;
    *(uint4*)&xsT[base+8] = u1;
  } else if (bx == 24){
    #pragma unroll
    for (int q=0;q<16;q++)
      Bn[(size_t)(b*DL + l0 + li*16 + q)*64 + c] = ov[q];
    size_t bt = (((size_t)(b*64 + by))*64 + c)*64 + li*16;
    uint4 u0,u1; pack16(ov,u0,u1);
    *(uint4*)&BT[bt]   = u0;
    *(uint4*)&BT[bt+8] = u1;
  } else {
    #pragma unroll
    for (int q=0;q<16;q++)
      Cn[(size_t)(b*DL + l0 + li*16 + q)*64 + c] = ov[q];
  }
}

// ---------------- K4: per-(b,h,chunk) logdA cumsum (fp32) ----------------
__global__ void cum_kernel(const float* __restrict__ dt, const float* __restrict__ A_log,
                           float* __restrict__ cum, float* __restrict__ dtT)
{
  int tid = threadIdx.x; int lane = tid&63; int wv = tid>>6;
  int idx = blockIdx.x*4 + wv;            // (b*24+h)*64 + ch
  int b = idx / 1536; int r = idx % 1536; int h = r >> 6; int chk = r & 63;
  float dv = dt[((size_t)(b*DL + chk*64 + lane))*DH + h];
  float ld = -dv * expf(A_log[h]);
  for (int off=1; off<64; off<<=1){
    float v = __shfl_up(ld, off);
    if (lane >= off) ld += v;
  }
  size_t cb = (size_t)idx*64;
  cum[cb + lane] = ld;
  dtT[cb + lane] = dv;
}

// ---------------- K5: FUSED chunked scan (phaseA+phaseB+phaseC) ----------------
// One block per (b,h); sequential over 64 chunks; running state h in fp32 LDS (never HBM).
// Eliminates the S/hinit 400MB round-trip and the 192-block serial phaseB kernel.
// Per chunk (verified phaseA/phaseC code blocks, re-ordered; 6 barriers):
//   stage C,B,X | G=C@B^T + Htb=bf16(Hf) | M build + Ct*=a_t + restage Bt<-BT |
//   Y = M@X + (aC)@Htb -> y | Xw=X*wl (into Mt) | S=Xw@BT^T, Hf = a63*Hf + S
__global__ void fused_scan_kernel(const unsigned short* __restrict__ Cn,
                                  const unsigned short* __restrict__ Bn,
                                  const unsigned short* __restrict__ xsT,
                                  const unsigned short* __restrict__ BT,
                                  const float* __restrict__ cum, const float* __restrict__ dtT,
                                  const float* __restrict__ D_skip,
                                  unsigned short* __restrict__ yout)
{
  int bh = blockIdx.x; int h = bh % DH; int b = bh / DH;
  int tid = threadIdx.x, lane = tid&63, wv = tid>>6;
  __shared__ __align__(16) unsigned short Ct[64*72];
  __shared__ __align__(16) unsigned short Bt[64*72];   // B(t,n) for G, then BT(n,t) for S
  __shared__ __align__(16) unsigned short Xt[64*72];
  __shared__ __align__(16) unsigned short Mt[64*72];   // M for Y1, then Xw for S
  __shared__ __align__(16) unsigned short Htb[64*72];  // bf16 h_prev (p,n)
  __shared__ float Hf[64*64];                          // fp32 running state (p,n)
  __shared__ float cumL[64], dtL[64], aL[64], wl[64];

  for (int i = tid; i < 64*64; i += 256) Hf[i] = 0.f;

  const int ml = lane&15, ko8 = (lane>>4)*8, r0 = (lane>>4)*4;
  const int t0 = (wv&1)*32, q0 = (wv>>1)*32;
  const int rr = tid>>2, cc = (tid&3)*16;
  const float dsk = D_skip[h];
  __syncthreads();                                    // Hf zero visible (acts as B0 for chk 0)

  for (int chk = 0; chk < NCH; ++chk){
    size_t cb = ((size_t)((b*DH+h)*64 + chk))*64;
    size_t tb = cb*64;
    size_t lrow = (size_t)(b*DL + chk*64 + rr);
    // ---- stage C (t,n), B (t,n), X (p,t) ----
    #pragma unroll
    for (int half=0; half<2; half++){
      int c8 = cc + half*8;
      *(uint4*)&Ct[rr*72 + c8] = *(const uint4*)&Cn[lrow*64 + c8];
      *(uint4*)&Bt[rr*72 + c8] = *(const uint4*)&Bn[lrow*64 + c8];
      *(uint4*)&Xt[rr*72 + c8] = *(const uint4*)&xsT[tb + rr*64 + c8];
    }
    if (tid < 64){
      float cv = cum[cb + tid];
      cumL[tid] = cv; aL[tid] = expf(cv); dtL[tid] = dtT[cb + tid];
    }
    __syncthreads();                                  // B1
    if (tid < 64) wl[tid] = expf(cumL[63] - cumL[tid]) * dtL[tid];
    // ---- Htb <- bf16(Hf) (h_prev snapshot) ----
    #pragma unroll
    for (int q=0;q<16;q++)
      Htb[rr*72 + cc + q] = f2bf(Hf[rr*64 + cc + q]);
    // ---- G = C @ B^T ----
    f32x4 accG[2][2];
    #pragma unroll
    for (int i=0;i<2;i++)
      #pragma unroll
      for (int j=0;j<2;j++) accG[i][j] = (f32x4){0.f,0.f,0.f,0.f};
    #pragma unroll
    for (int kn=0; kn<64; kn+=32){
      bf16x8 a0 = *(const bf16x8*)&Ct[(t0+ml)*72    + kn + ko8];
      bf16x8 a1 = *(const bf16x8*)&Ct[(t0+16+ml)*72 + kn + ko8];
      bf16x8 b0 = *(const bf16x8*)&Bt[(q0+ml)*72    + kn + ko8];
      bf16x8 b1 = *(const bf16x8*)&Bt[(q0+16+ml)*72 + kn + ko8];
      accG[0][0] = __builtin_amdgcn_mfma_f32_16x16x32_bf16(a0,b0,accG[0][0],0,0,0);
      accG[0][1] = __builtin_amdgcn_mfma_f32_16x16x32_bf16(a0,b1,accG[0][1],0,0,0);
      accG[1][0] = __builtin_amdgcn_mfma_f32_16x16x32_bf16(a1,b0,accG[1][0],0,0,0);
      accG[1][1] = __builtin_amdgcn_mfma_f32_16x16x32_bf16(a1,b1,accG[1][1],0,0,0);
    }
    __syncthreads();                                  // B2 (G done: Bt free, Mt free)
    // ---- M[t][s] = (s<=t) ? G * exp(cum_t-cum_s) * dt_s : 0 ----
    #pragma unroll
    for (int i=0;i<2;i++){
      #pragma unroll
      for (int j=0;j<2;j++){
        int s = q0 + j*16 + ml;
        int tbs = t0 + i*16 + r0;
        #pragma unroll
        for (int r=0;r<4;r++){
          int t = tbs + r;
          float m = 0.f;
          if (s <= t) m = accG[i][j][r] * expf(cumL[t]-cumL[s]) * dtL[s];
          Mt[t*72 + s] = f2bf(m);
        }
      }
    }
    // ---- Ct <- a_t * Ct (in place) ----
    {
      float at = aL[rr];
      #pragma unroll
      for (int q=0;q<16;q++){
        int idx = rr*72 + cc + q;
        Ct[idx] = f2bf(bf2f(Ct[idx]) * at);
      }
    }
    // ---- restage Bt <- BT (n,t) for the S-GEMM ----
    {
      size_t btb = ((size_t)(b*64 + chk))*4096;
      #pragma unroll
      for (int half=0; half<2; half++){
        int c8 = cc + half*8;
        *(uint4*)&Bt[rr*72 + c8] = *(const uint4*)&BT[btb + rr*64 + c8];
      }
    }
    __syncthreads();                                  // B3
    // ---- Y = M@X + (aC)@Htb ; write y ----
    f32x4 accY[2][2];
    #pragma unroll
    for (int i=0;i<2;i++)
      #pragma unroll
      for (int j=0;j<2;j++) accY[i][j] = (f32x4){0.f,0.f,0.f,0.f};
    #pragma unroll
    for (int ks=0; ks<64; ks+=32){
      bf16x8 a0 = *(const bf16x8*)&Mt[(t0+ml)*72    + ks + ko8];
      bf16x8 a1 = *(const bf16x8*)&Mt[(t0+16+ml)*72 + ks + ko8];
      bf16x8 b0 = *(const bf16x8*)&Xt[(q0+ml)*72    + ks + ko8];
      bf16x8 b1 = *(const bf16x8*)&Xt[(q0+16+ml)*72 + ks + ko8];
      accY[0][0] = __builtin_amdgcn_mfma_f32_16x16x32_bf16(a0,b0,accY[0][0],0,0,0);
      accY[0][1] = __builtin_amdgcn_mfma_f32_16x16x32_bf16(a0,b1,accY[0][1],0,0,0);
      accY[1][0] = __builtin_amdgcn_mfma_f32_16x16x32_bf16(a1,b0,accY[1][0],0,0,0);
      accY[1][1] = __builtin_amdgcn_mfma_f32_16x16x32_bf16(a1,b1,accY[1][1],0,0,0);
    }
    #pragma unroll
    for (int kn=0; kn<64; kn+=32){
      bf16x8 a0 = *(const bf16x8*)&Ct[(t0+ml)*72    + kn + ko8];
      bf16x8 a1 = *(const bf16x8*)&Ct[(t0+16+ml)*72 + kn + ko8];
      bf16x8 b0 = *(const bf16x8*)&Htb[(q0+ml)*72    + kn + ko8];
      bf16x8 b1 = *(const bf16x8*)&Htb[(q0+16+ml)*72 + kn + ko8];
      accY[0][0] = __builtin_amdgcn_mfma_f32_16x16x32_bf16(a0,b0,accY[0][0],0,0,0);
      accY[0][1] = __builtin_amdgcn_mfma_f32_16x16x32_bf16(a0,b1,accY[0][1],0,0,0);
      accY[1][0] = __builtin_amdgcn_mfma_f32_16x16x32_bf16(a1,b0,accY[1][0],0,0,0);
      accY[1][1] = __builtin_amdgcn_mfma_f32_16x16x32_bf16(a1,b1,accY[1][1],0,0,0);
    }
    #pragma unroll
    for (int i=0;i<2;i++){
      #pragma unroll
      for (int j=0;j<2;j++){
        int p = q0 + j*16 + ml;
        int tbs = t0 + i*16 + r0;
        #pragma unroll
        for (int r=0;r<4;r++){
          int t = tbs + r;
          float xv = bf2f(Xt[p*72 + t]);
          float v = accY[i][j][r] + dsk*xv;
          yout[(size_t)(b*DL + chk*64 + t)*ZLD + 1536 + h*64 + p] = f2bf(v);
        }
      }
    }
    __syncthreads();                                  // B4 (Y done: Mt, Xt, Htb free)
    // ---- Xw[p][t] = X[p][t] * wl[t] into Mt ----
    #pragma unroll
    for (int q=0;q<16;q++){
      int t = cc + q;
      Mt[rr*72 + t] = f2bf(bf2f(Xt[rr*72 + t]) * wl[t]);
    }
    __syncthreads();                                  // B5
    // ---- S = Xw @ BT^T ; Hf = a63*Hf + S ----
    f32x4 accS[2][2];
    #pragma unroll
    for (int i=0;i<2;i++)
      #pragma unroll
      for (int j=0;j<2;j++) accS[i][j] = (f32x4){0.f,0.f,0.f,0.f};
    #pragma unroll
    for (int ks=0; ks<64; ks+=32){
      bf16x8 a0 = *(const bf16x8*)&Mt[(t0+ml)*72    + ks + ko8];
      bf16x8 a1 = *(const bf16x8*)&Mt[(t0+16+ml)*72 + ks + ko8];
      bf16x8 b0 = *(const bf16x8*)&Bt[(q0+ml)*72    + ks + ko8];
      bf16x8 b1 = *(const bf16x8*)&Bt[(q0+16+ml)*72 + ks + ko8];
      accS[0][0] = __builtin_amdgcn_mfma_f32_16x16x32_bf16(a0,b0,accS[0][0],0,0,0);
      accS[0][1] = __builtin_amdgcn_mfma_f32_16x16x32_bf16(a0,b1,accS[0][1],0,0,0);
      accS[1][0] = __builtin_amdgcn_mfma_f32_16x16x32_bf16(a1,b0,accS[1][0],0,0,0);
      accS[1][1] = __builtin_amdgcn_mfma_f32_16x16x32_bf16(a1,b1,accS[1][1],0,0,0);
    }
    {
      float a63 = aL[63];
      #pragma unroll
      for (int i=0;i<2;i++){
        #pragma unroll
        for (int j=0;j<2;j++){
          int n = q0 + j*16 + ml;
          int pr = t0 + i*16 + r0;
          #pragma unroll
          for (int r=0;r<4;r++){
            int idx = (pr+r)*64 + n;
            Hf[idx] = Hf[idx]*a63 + accS[i][j][r];
          }
        }
      }
    }
    __syncthreads();                                  // B0: Hf update + S reads done before restage
  }
}

// ---------------- K8: gating + RMSNorm -> g (IN PLACE over z cols of zx) ----------------
__global__ void gate_kernel(unsigned short* __restrict__ zx,
                            const float* __restrict__ nw)
{
  int row = blockIdx.x; int tid = threadIdx.x;
  unsigned short* zr = zx + (size_t)row*ZLD;       // z cols [0,1536), y cols [1536,3072)
  float gv[6]; float s2 = 0.f;
  #pragma unroll
  for (int k=0;k<6;k++){
    int i = tid + k*256;
    float yv = bf2f(zr[1536 + i]);
    float zv = bf2f(zr[i]);
    float t = yv * siluf(zv);
    gv[k] = t; s2 += t*t;
  }
  for (int off=32; off>0; off>>=1) s2 += __shfl_down(s2, off);
  __shared__ float red[5];
  int wv = tid>>6;
  if ((tid&63)==0) red[wv] = s2;
  __syncthreads();
  if (tid==0) red[4] = red[0]+red[1]+red[2]+red[3];
  __syncthreads();
  float scale = rsqrtf(red[4]*(1.f/1536.f) + 1e-5f);
  #pragma unroll
  for (int k=0;k<6;k++){
    int i = tid + k*256;
    zr[i] = f2bf(gv[k]*scale*nw[i]);   // g overwrites z in place (each thread wrote only what it read)
  }
}

// ---------------- launch ----------------
extern "C" void kernel_launch(void* const* d_in, const int* in_sizes, int n_in,
                              void* d_out, int out_size, void* d_ws, size_t ws_size,
                              hipStream_t stream)
{
  (void)in_sizes; (void)n_in; (void)out_size; (void)ws_size;
  const float* x      = (const float*)d_in[0];
  const float* ln_w   = (const float*)d_in[1];
  const float* ln_b   = (const float*)d_in[2];
  const float* Win    = (const float*)d_in[3];
  const float* conv_w = (const float*)d_in[4];
  const float* conv_b = (const float*)d_in[5];
  const float* dt_bias= (const float*)d_in[6];
  const float* A_log  = (const float*)d_in[7];
  const float* D_skip = (const float*)d_in[8];
  const float* norm_w = (const float*)d_in[9];
  const float* Wout   = (const float*)d_in[10];
  float* out = (float*)d_out;
  char* ws = (char*)d_ws;

  // ws layout (total ~340 MB). S/hinit arrays eliminated by the fused scan.
  unsigned short* zx    = (unsigned short*)(ws + 0);            // 209,715,200  (z | xBC; y overlays xBC; g overlays z)
  unsigned short* xsT   = (unsigned short*)(ws + 209715200);    // 100,663,296  (xn overlaid: disjoint lifetime)
  unsigned short* xn    = xsT;                                  //  50,331,648  (dead after GEMM1, before conv writes xsT)
  unsigned short* winb  = (unsigned short*)(ws + 310378496);    //   4,952,064
  unsigned short* woutb = (unsigned short*)(ws + 315330560);    //   2,359,296
  float*          dtb   = (float*)        (ws + 317689856);     //   3,145,728
  float*          dtT   = (float*)        (ws + 320835584);     //   3,145,728
  float*          cum   = (float*)        (ws + 323981312);     //   3,145,728
  unsigned short* Bn    = (unsigned short*)(ws + 327127040);    //   4,194,304
  unsigned short* Cn    = (unsigned short*)(ws + 331321344);    //   4,194,304
  unsigned short* BT    = (unsigned short*)(ws + 335515648);    //   4,194,304  (end 339,709,952)

  cvt_kernel  <<<3570, 256, 0, stream>>>(Win, Wout, winb, woutb);
  ln_kernel   <<<BL, 256, 0, stream>>>(x, ln_w, ln_b, xn);
  gemm_kernel<1><<<256*26, 256, 0, stream>>>(xn, winb, 768, 768, DIPD, 26, zx, dtb, dt_bias, nullptr, nullptr);
  conv_kernel <<<dim3(26,64,8), 256, 0, stream>>>(zx, conv_w, conv_b, xsT, Bn, Cn, BT);
  cum_kernel  <<<3072, 256, 0, stream>>>(dtb, A_log, cum, dtT);
  fused_scan_kernel<<<DB*DH, 256, 0, stream>>>(Cn, Bn, xsT, BT, cum, dtT, D_skip, zx);
  gate_kernel <<<BL, 256, 0, stream>>>(zx, norm_w);
  gemm_kernel<2><<<256*6, 256, 0, stream>>>(zx, woutb, 1536, ZLD, DD, 6, nullptr, nullptr, nullptr, x, out);
}

// Round 9
// 910.428 us; speedup vs baseline: 1.0697x; 1.0697x over previous
//
#include <hip/hip_runtime.h>
#include <cstdint>

// Problem dims
#define DB   8
#define DL   4096
#define DD   768
#define DDI  1536
#define DN   64
#define DH   24
#define DP   64
#define DCD  1664
#define DIPD 3224
#define BL   (DB*DL)      // 32768 tokens
#define NCH  64           // chunks (L/64)
#define ZLD  3200         // zx row stride (z 1536 | xBC 1664)

typedef __attribute__((ext_vector_type(8))) short bf16x8;
typedef __attribute__((ext_vector_type(4))) float f32x4;

__device__ __forceinline__ unsigned short f2bf(float f){
  unsigned u = __float_as_uint(f);
  u += 0x7FFFu + ((u >> 16) & 1u);
  return (unsigned short)(u >> 16);
}
__device__ __forceinline__ float bf2f(unsigned short s){
  return __uint_as_float(((unsigned)s) << 16);
}
__device__ __forceinline__ unsigned pack2(unsigned short a, unsigned short b){
  return (unsigned)a | ((unsigned)b << 16);
}
__device__ __forceinline__ void pack16(const unsigned short* ov, uint4& u0, uint4& u1){
  u0.x = pack2(ov[0],ov[1]);  u0.y = pack2(ov[2],ov[3]);
  u0.z = pack2(ov[4],ov[5]);  u0.w = pack2(ov[6],ov[7]);
  u1.x = pack2(ov[8],ov[9]);  u1.y = pack2(ov[10],ov[11]);
  u1.z = pack2(ov[12],ov[13]); u1.w = pack2(ov[14],ov[15]);
}
__device__ __forceinline__ void async16(void* lds, const void* g){
  __builtin_amdgcn_global_load_lds((const __attribute__((address_space(1))) unsigned*)g,
                                   (__attribute__((address_space(3))) unsigned*)lds, 16, 0, 0);
}
__device__ __forceinline__ float softplusf(float v){
  return v > 15.f ? v : log1pf(expf(v));
}
__device__ __forceinline__ float siluf(float v){
  return v / (1.f + expf(-v));
}

// ---------------- K0: fp32 -> bf16 weight conversion (Win, Wout) ----------------
__global__ void cvt_kernel(const float* __restrict__ win, const float* __restrict__ wout,
                           unsigned short* __restrict__ winb, unsigned short* __restrict__ woutb){
  int i = blockIdx.x*256 + threadIdx.x;
  const int WN = (DIPD*DD)/4;   // 619008
  const int ON = (DD*DDI)/4;    // 294912
  if (i < WN){
    float4 v = ((const float4*)win)[i];
    uint2 o; o.x = pack2(f2bf(v.x), f2bf(v.y)); o.y = pack2(f2bf(v.z), f2bf(v.w));
    ((uint2*)winb)[i] = o;
  } else if (i < WN+ON){
    int j = i - WN;
    float4 v = ((const float4*)wout)[j];
    uint2 o; o.x = pack2(f2bf(v.x), f2bf(v.y)); o.y = pack2(f2bf(v.z), f2bf(v.w));
    ((uint2*)woutb)[j] = o;
  }
}

// ---------------- K1: LayerNorm -> xn (bf16) ----------------
__global__ void ln_kernel(const float* __restrict__ x, const float* __restrict__ w,
                          const float* __restrict__ bb, unsigned short* __restrict__ xn){
  int row = blockIdx.x; int tid = threadIdx.x;
  const float* xr = x + (size_t)row*DD;
  float v0=xr[tid], v1=xr[tid+256], v2=xr[tid+512];
  float s = v0+v1+v2;
  float s2 = v0*v0+v1*v1+v2*v2;
  for (int off=32; off>0; off>>=1){ s += __shfl_down(s, off); s2 += __shfl_down(s2, off); }
  __shared__ float red[10];
  int wv = tid>>6;
  if ((tid&63)==0){ red[wv]=s; red[4+wv]=s2; }
  __syncthreads();
  if (tid==0){
    float a=red[0]+red[1]+red[2]+red[3];
    float c=red[4]+red[5]+red[6]+red[7];
    red[8]=a*(1.f/768.f); red[9]=c*(1.f/768.f);
  }
  __syncthreads();
  float mu = red[8];
  float inv = rsqrtf(red[9]-mu*mu + 1e-5f);
  unsigned short* o = xn + (size_t)row*DD;
  o[tid]     = f2bf((v0-mu)*inv*w[tid]     + bb[tid]);
  o[tid+256] = f2bf((v1-mu)*inv*w[tid+256] + bb[tid+256]);
  o[tid+512] = f2bf((v2-mu)*inv*w[tid+512] + bb[tid+512]);
}

// ---------------- K2: bf16 MFMA GEMM (128x128, BK=32, dbuf, conflict-free swizzle) ----------------
// Settled structure (rounds 1-6): 2-phase latency-bound ceiling ~660 TF at this shape.
template<int MODE>
__launch_bounds__(256,4)
__global__ void gemm_kernel(const unsigned short* __restrict__ A,
                            const unsigned short* __restrict__ Bw,
                            int K, int lda, int Brows, int nbn,
                            unsigned short* __restrict__ zx, float* __restrict__ dtbuf,
                            const float* __restrict__ dt_bias,
                            const float* __restrict__ xres, float* __restrict__ outp)
{
  __shared__ __align__(16) unsigned short As[2*128*32];   // 16 KiB x2
  __shared__ __align__(16) unsigned short Bs[2*128*32];
  int tid = threadIdx.x; int lane = tid&63; int wv = tid>>6;
  int nwg  = gridDim.x;
  int orig = blockIdx.x;
  int q    = nwg >> 3;
  int wgid = (orig & 7)*q + (orig >> 3);
  int bm = wgid / nbn, bn = wgid % nbn;

  const int gc = ((lane&3) ^ ((lane>>3)&3)) * 8;
  const unsigned short* ap0 = A + (size_t)(bm*128 + wv*32 + (lane>>2))*lda + gc;
  const unsigned short* ap1 = ap0 + (size_t)16*lda;
  int rb0 = bn*128 + wv*32 + (lane>>2);      if (rb0 > Brows-1) rb0 = Brows-1;
  int rb1 = bn*128 + wv*32 + 16 + (lane>>2); if (rb1 > Brows-1) rb1 = Brows-1;
  const unsigned short* bp0 = Bw + (size_t)rb0*K + gc;
  const unsigned short* bp1 = Bw + (size_t)rb1*K + gc;
  unsigned short* la0 = &As[(wv*2)*512]; unsigned short* la1 = la0 + 512;
  unsigned short* lb0 = &Bs[(wv*2)*512]; unsigned short* lb1 = lb0 + 512;
  f32x4 acc[4][4];
  #pragma unroll
  for (int i=0;i<4;i++)
    #pragma unroll
    for (int j=0;j<4;j++) acc[i][j] = (f32x4){0.f,0.f,0.f,0.f};
  int mb = (wv&1)*64 + (lane&15);
  int nb = (wv>>1)*64 + (lane&15);
  const int cswz = ((lane>>4) ^ ((lane>>1)&3)) * 8;

  async16(la0, ap0); async16(la1, ap1);
  async16(lb0, bp0); async16(lb1, bp1);
  ap0 += 32; ap1 += 32; bp0 += 32; bp1 += 32;
  __syncthreads();

  int cur = 0;
  for (int k0=0; k0<K; k0+=32){
    if (k0 + 32 < K){
      int nxt = (cur^1)*4096;
      async16(la0 + nxt, ap0); async16(la1 + nxt, ap1);
      async16(lb0 + nxt, bp0); async16(lb1 + nxt, bp1);
      ap0 += 32; ap1 += 32; bp0 += 32; bp1 += 32;
    }
    const unsigned short* Ab = &As[cur*4096];
    const unsigned short* Bb = &Bs[cur*4096];
    bf16x8 af[4], bfr[4];
    #pragma unroll
    for (int i=0;i<4;i++) af[i]  = *(const bf16x8*)&Ab[(mb+i*16)*32 + cswz];
    #pragma unroll
    for (int j=0;j<4;j++) bfr[j] = *(const bf16x8*)&Bb[(nb+j*16)*32 + cswz];
    #pragma unroll
    for (int i=0;i<4;i++)
      #pragma unroll
      for (int j=0;j<4;j++)
        acc[i][j] = __builtin_amdgcn_mfma_f32_16x16x32_bf16(af[i], bfr[j], acc[i][j], 0, 0, 0);
    __syncthreads();
    cur ^= 1;
  }

  int mrow0 = bm*128 + (wv&1)*64 + (lane>>4)*4;
  int ncol0 = bn*128 + (wv>>1)*64 + (lane&15);
  #pragma unroll
  for (int i=0;i<4;i++){
    #pragma unroll
    for (int j=0;j<4;j++){
      int col = ncol0 + j*16;
      #pragma unroll
      for (int r=0;r<4;r++){
        int row = mrow0 + i*16 + r;
        float v = acc[i][j][r];
        if (MODE == 1){
          if (bn < 25){
            zx[(size_t)row*ZLD + col] = f2bf(v);
          } else {
            int cc = col - 3200;
            if (cc >= 0 && cc < DH) dtbuf[(size_t)row*DH + cc] = softplusf(v + dt_bias[cc]);
          }
        } else {
          float xr = __builtin_nontemporal_load(&xres[(size_t)row*DD + col]);
          __builtin_nontemporal_store(v + xr, &outp[(size_t)row*DD + col]);
        }
      }
    }
  }
}

// ---------------- K3: depthwise causal conv K=4 + bias + silu ----------------
__global__ void conv_kernel(const unsigned short* __restrict__ zx,
                            const float* __restrict__ cw, const float* __restrict__ cb,
                            unsigned short* __restrict__ xsT, unsigned short* __restrict__ Bn,
                            unsigned short* __restrict__ Cn, unsigned short* __restrict__ BT)
{
  int bx = blockIdx.x, by = blockIdx.y, b = blockIdx.z;
  int tid = threadIdx.x;
  __shared__ __align__(16) unsigned short in_s[67*64];
  int l0 = by*64;
  for (int idx = tid; idx < 67*8; idx += 256){
    int r = idx >> 3, c8 = idx & 7;
    int l = l0 - 3 + r;
    uint4 v = make_uint4(0u,0u,0u,0u);
    if (l >= 0) v = *(const uint4*)&zx[(size_t)(b*DL + l)*ZLD + 1536 + bx*64 + c8*8];
    *(uint4*)&in_s[r*64 + c8*8] = v;
  }
  __syncthreads();
  int c = tid & 63, li = tid >> 6;
  int chn = bx*64 + c;
  float w0=cw[chn*4+0], w1=cw[chn*4+1], w2=cw[chn*4+2], w3=cw[chn*4+3];
  float bias = cb[chn];
  unsigned short ov[16];
  #pragma unroll
  for (int q=0;q<16;q++){
    int t = li*16 + q;
    float a = bias
      + w0*bf2f(in_s[(t+0)*64 + c])
      + w1*bf2f(in_s[(t+1)*64 + c])
      + w2*bf2f(in_s[(t+2)*64 + c])
      + w3*bf2f(in_s[(t+3)*64 + c]);
    ov[q] = f2bf(siluf(a));
  }
  if (bx < 24){
    size_t base = ((((size_t)(b*DH + bx))*64 + by)*64 + c)*64 + li*16;
    uint4 u0,u1; pack16(ov,u0,u1);
    *(uint4*)&xsT[base]   = u0;
    *(uint4*)&xsT[base+8] = u1;
  } else if (bx == 24){
    #pragma unroll
    for (int q=0;q<16;q++)
      Bn[(size_t)(b*DL + l0 + li*16 + q)*64 + c] = ov[q];
    size_t bt = (((size_t)(b*64 + by))*64 + c)*64 + li*16;
    uint4 u0,u1; pack16(ov,u0,u1);
    *(uint4*)&BT[bt]   = u0;
    *(uint4*)&BT[bt+8] = u1;
  } else {
    #pragma unroll
    for (int q=0;q<16;q++)
      Cn[(size_t)(b*DL + l0 + li*16 + q)*64 + c] = ov[q];
  }
}

// ---------------- K4: per-(b,h,chunk) logdA cumsum (fp32) ----------------
__global__ void cum_kernel(const float* __restrict__ dt, const float* __restrict__ A_log,
                           float* __restrict__ cum, float* __restrict__ dtT)
{
  int tid = threadIdx.x; int lane = tid&63; int wv = tid>>6;
  int idx = blockIdx.x*4 + wv;            // (b*24+h)*64 + ch
  int b = idx / 1536; int r = idx % 1536; int h = r >> 6; int chk = r & 63;
  float dv = dt[((size_t)(b*DL + chk*64 + lane))*DH + h];
  float ld = -dv * expf(A_log[h]);
  for (int off=1; off<64; off<<=1){
    float v = __shfl_up(ld, off);
    if (lane >= off) ld += v;
  }
  size_t cb = (size_t)idx*64;
  cum[cb + lane] = ld;
  dtT[cb + lane] = dv;
}

// ---------------- K5: FUSED chunked scan (phaseA+phaseB+phaseC) + T14 prefetch ----------------
// Deltas vs round-7 (320us, MfmaUtil 3%, Occ 8.8% -> pure latency trap):
//  1. T14 async-STAGE split: chunk k+1's C/B/X/BT (8 uint4/thread) + cum/dt scalars are
//     loaded into NAMED registers right after barrier B1 of chunk k; LDS writes happen at
//     the top of chunk k+1. ~900cy HBM latency hides under the G/M/Y/S compute.
//     (BT of the CURRENT chunk is copied to locals before the prefetch overwrites it.)
//  2. Hf stride 64 -> 65: old stride-64 fp32 rows put all 64 lanes in 2 banks (32-way,
//     1.34e7 conflicts). (rr*65+cc+q) -> bank (rr+cc+q)&31 = uniform 2-way (free).
__global__ void fused_scan_kernel(const unsigned short* __restrict__ Cn,
                                  const unsigned short* __restrict__ Bn,
                                  const unsigned short* __restrict__ xsT,
                                  const unsigned short* __restrict__ BT,
                                  const float* __restrict__ cum, const float* __restrict__ dtT,
                                  const float* __restrict__ D_skip,
                                  unsigned short* __restrict__ yout)
{
  int bh = blockIdx.x; int h = bh % DH; int b = bh / DH;
  int tid = threadIdx.x, lane = tid&63, wv = tid>>6;
  __shared__ __align__(16) unsigned short Ct[64*72];
  __shared__ __align__(16) unsigned short Bt[64*72];   // B(t,n) for G, then BT(n,t) for S
  __shared__ __align__(16) unsigned short Xt[64*72];
  __shared__ __align__(16) unsigned short Mt[64*72];   // M for Y1, then Xw for S
  __shared__ __align__(16) unsigned short Htb[64*72];  // bf16 h_prev (p,n)
  __shared__ float Hf[64*65];                          // fp32 running state (p,n), padded stride
  __shared__ float cumL[64], dtL[64], aL[64], wl[64];

  for (int i = tid; i < 64*65; i += 256) Hf[i] = 0.f;

  const int ml = lane&15, ko8 = (lane>>4)*8, r0 = (lane>>4)*4;
  const int t0 = (wv&1)*32, q0 = (wv>>1)*32;
  const int rr = tid>>2, cc = (tid&3)*16;
  const float dsk = D_skip[h];

  // ---- prologue: prefetch chunk 0 into registers ----
  uint4 rC0,rC1,rB0,rB1,rX0,rX1,rT0,rT1;
  float pcum = 0.f, pdt = 0.f;
  {
    size_t cb0 = ((size_t)((b*DH+h)*64 + 0))*64;
    size_t tb0 = cb0*64;
    size_t lrow0 = (size_t)(b*DL + rr);
    size_t btb0 = ((size_t)(b*64 + 0))*4096;
    rC0 = *(const uint4*)&Cn[lrow0*64 + cc];     rC1 = *(const uint4*)&Cn[lrow0*64 + cc + 8];
    rB0 = *(const uint4*)&Bn[lrow0*64 + cc];     rB1 = *(const uint4*)&Bn[lrow0*64 + cc + 8];
    rX0 = *(const uint4*)&xsT[tb0 + rr*64 + cc]; rX1 = *(const uint4*)&xsT[tb0 + rr*64 + cc + 8];
    rT0 = *(const uint4*)&BT[btb0 + rr*64 + cc]; rT1 = *(const uint4*)&BT[btb0 + rr*64 + cc + 8];
    if (tid < 64){ pcum = cum[cb0 + tid]; pdt = dtT[cb0 + tid]; }
  }
  __syncthreads();                                    // Hf zero visible

  for (int chk = 0; chk < NCH; ++chk){
    // ---- write prefetched regs to LDS ----
    *(uint4*)&Ct[rr*72 + cc]     = rC0;  *(uint4*)&Ct[rr*72 + cc + 8] = rC1;
    *(uint4*)&Bt[rr*72 + cc]     = rB0;  *(uint4*)&Bt[rr*72 + cc + 8] = rB1;
    *(uint4*)&Xt[rr*72 + cc]     = rX0;  *(uint4*)&Xt[rr*72 + cc + 8] = rX1;
    if (tid < 64){
      cumL[tid] = pcum; aL[tid] = expf(pcum); dtL[tid] = pdt;
    }
    __syncthreads();                                  // B1
    // hold current chunk's BT (needed mid-chunk) before prefetch overwrites
    uint4 curT0 = rT0, curT1 = rT1;
    // ---- T14: prefetch chunk k+1 (lands under this chunk's compute) ----
    if (chk + 1 < NCH){
      size_t cbn = ((size_t)((b*DH+h)*64 + (chk+1)))*64;
      size_t tbn = cbn*64;
      size_t lrown = (size_t)(b*DL + (chk+1)*64 + rr);
      size_t btbn = ((size_t)(b*64 + (chk+1)))*4096;
      rC0 = *(const uint4*)&Cn[lrown*64 + cc];     rC1 = *(const uint4*)&Cn[lrown*64 + cc + 8];
      rB0 = *(const uint4*)&Bn[lrown*64 + cc];     rB1 = *(const uint4*)&Bn[lrown*64 + cc + 8];
      rX0 = *(const uint4*)&xsT[tbn + rr*64 + cc]; rX1 = *(const uint4*)&xsT[tbn + rr*64 + cc + 8];
      rT0 = *(const uint4*)&BT[btbn + rr*64 + cc]; rT1 = *(const uint4*)&BT[btbn + rr*64 + cc + 8];
      if (tid < 64){ pcum = cum[cbn + tid]; pdt = dtT[cbn + tid]; }
    }
    if (tid < 64) wl[tid] = expf(cumL[63] - cumL[tid]) * dtL[tid];
    // ---- Htb <- bf16(Hf) (h_prev snapshot) ----
    #pragma unroll
    for (int q=0;q<16;q++)
      Htb[rr*72 + cc + q] = f2bf(Hf[rr*65 + cc + q]);
    // ---- G = C @ B^T ----
    f32x4 accG[2][2];
    #pragma unroll
    for (int i=0;i<2;i++)
      #pragma unroll
      for (int j=0;j<2;j++) accG[i][j] = (f32x4){0.f,0.f,0.f,0.f};
    #pragma unroll
    for (int kn=0; kn<64; kn+=32){
      bf16x8 a0 = *(const bf16x8*)&Ct[(t0+ml)*72    + kn + ko8];
      bf16x8 a1 = *(const bf16x8*)&Ct[(t0+16+ml)*72 + kn + ko8];
      bf16x8 b0 = *(const bf16x8*)&Bt[(q0+ml)*72    + kn + ko8];
      bf16x8 b1 = *(const bf16x8*)&Bt[(q0+16+ml)*72 + kn + ko8];
      accG[0][0] = __builtin_amdgcn_mfma_f32_16x16x32_bf16(a0,b0,accG[0][0],0,0,0);
      accG[0][1] = __builtin_amdgcn_mfma_f32_16x16x32_bf16(a0,b1,accG[0][1],0,0,0);
      accG[1][0] = __builtin_amdgcn_mfma_f32_16x16x32_bf16(a1,b0,accG[1][0],0,0,0);
      accG[1][1] = __builtin_amdgcn_mfma_f32_16x16x32_bf16(a1,b1,accG[1][1],0,0,0);
    }
    __syncthreads();                                  // B2 (G done: Bt free, Mt free)
    // ---- M[t][s] = (s<=t) ? G * exp(cum_t-cum_s) * dt_s : 0 ----
    #pragma unroll
    for (int i=0;i<2;i++){
      #pragma unroll
      for (int j=0;j<2;j++){
        int s = q0 + j*16 + ml;
        int tbs = t0 + i*16 + r0;
        #pragma unroll
        for (int r=0;r<4;r++){
          int t = tbs + r;
          float m = 0.f;
          if (s <= t) m = accG[i][j][r] * expf(cumL[t]-cumL[s]) * dtL[s];
          Mt[t*72 + s] = f2bf(m);
        }
      }
    }
    // ---- Ct <- a_t * Ct (in place) ----
    {
      float at = aL[rr];
      #pragma unroll
      for (int q=0;q<16;q++){
        int idx = rr*72 + cc + q;
        Ct[idx] = f2bf(bf2f(Ct[idx]) * at);
      }
    }
    // ---- restage Bt <- BT (n,t) from held registers ----
    *(uint4*)&Bt[rr*72 + cc]     = curT0;
    *(uint4*)&Bt[rr*72 + cc + 8] = curT1;
    __syncthreads();                                  // B3
    // ---- Y = M@X + (aC)@Htb ; write y ----
    f32x4 accY[2][2];
    #pragma unroll
    for (int i=0;i<2;i++)
      #pragma unroll
      for (int j=0;j<2;j++) accY[i][j] = (f32x4){0.f,0.f,0.f,0.f};
    #pragma unroll
    for (int ks=0; ks<64; ks+=32){
      bf16x8 a0 = *(const bf16x8*)&Mt[(t0+ml)*72    + ks + ko8];
      bf16x8 a1 = *(const bf16x8*)&Mt[(t0+16+ml)*72 + ks + ko8];
      bf16x8 b0 = *(const bf16x8*)&Xt[(q0+ml)*72    + ks + ko8];
      bf16x8 b1 = *(const bf16x8*)&Xt[(q0+16+ml)*72 + ks + ko8];
      accY[0][0] = __builtin_amdgcn_mfma_f32_16x16x32_bf16(a0,b0,accY[0][0],0,0,0);
      accY[0][1] = __builtin_amdgcn_mfma_f32_16x16x32_bf16(a0,b1,accY[0][1],0,0,0);
      accY[1][0] = __builtin_amdgcn_mfma_f32_16x16x32_bf16(a1,b0,accY[1][0],0,0,0);
      accY[1][1] = __builtin_amdgcn_mfma_f32_16x16x32_bf16(a1,b1,accY[1][1],0,0,0);
    }
    #pragma unroll
    for (int kn=0; kn<64; kn+=32){
      bf16x8 a0 = *(const bf16x8*)&Ct[(t0+ml)*72    + kn + ko8];
      bf16x8 a1 = *(const bf16x8*)&Ct[(t0+16+ml)*72 + kn + ko8];
      bf16x8 b0 = *(const bf16x8*)&Htb[(q0+ml)*72    + kn + ko8];
      bf16x8 b1 = *(const bf16x8*)&Htb[(q0+16+ml)*72 + kn + ko8];
      accY[0][0] = __builtin_amdgcn_mfma_f32_16x16x32_bf16(a0,b0,accY[0][0],0,0,0);
      accY[0][1] = __builtin_amdgcn_mfma_f32_16x16x32_bf16(a0,b1,accY[0][1],0,0,0);
      accY[1][0] = __builtin_amdgcn_mfma_f32_16x16x32_bf16(a1,b0,accY[1][0],0,0,0);
      accY[1][1] = __builtin_amdgcn_mfma_f32_16x16x32_bf16(a1,b1,accY[1][1],0,0,0);
    }
    #pragma unroll
    for (int i=0;i<2;i++){
      #pragma unroll
      for (int j=0;j<2;j++){
        int p = q0 + j*16 + ml;
        int tbs = t0 + i*16 + r0;
        #pragma unroll
        for (int r=0;r<4;r++){
          int t = tbs + r;
          float xv = bf2f(Xt[p*72 + t]);
          float v = accY[i][j][r] + dsk*xv;
          yout[(size_t)(b*DL + chk*64 + t)*ZLD + 1536 + h*64 + p] = f2bf(v);
        }
      }
    }
    __syncthreads();                                  // B4 (Y done: Mt, Xt, Htb free)
    // ---- Xw[p][t] = X[p][t] * wl[t] into Mt ----
    #pragma unroll
    for (int q=0;q<16;q++){
      int t = cc + q;
      Mt[rr*72 + t] = f2bf(bf2f(Xt[rr*72 + t]) * wl[t]);
    }
    __syncthreads();                                  // B5
    // ---- S = Xw @ BT^T ; Hf = a63*Hf + S ----
    f32x4 accS[2][2];
    #pragma unroll
    for (int i=0;i<2;i++)
      #pragma unroll
      for (int j=0;j<2;j++) accS[i][j] = (f32x4){0.f,0.f,0.f,0.f};
    #pragma unroll
    for (int ks=0; ks<64; ks+=32){
      bf16x8 a0 = *(const bf16x8*)&Mt[(t0+ml)*72    + ks + ko8];
      bf16x8 a1 = *(const bf16x8*)&Mt[(t0+16+ml)*72 + ks + ko8];
      bf16x8 b0 = *(const bf16x8*)&Bt[(q0+ml)*72    + ks + ko8];
      bf16x8 b1 = *(const bf16x8*)&Bt[(q0+16+ml)*72 + ks + ko8];
      accS[0][0] = __builtin_amdgcn_mfma_f32_16x16x32_bf16(a0,b0,accS[0][0],0,0,0);
      accS[0][1] = __builtin_amdgcn_mfma_f32_16x16x32_bf16(a0,b1,accS[0][1],0,0,0);
      accS[1][0] = __builtin_amdgcn_mfma_f32_16x16x32_bf16(a1,b0,accS[1][0],0,0,0);
      accS[1][1] = __builtin_amdgcn_mfma_f32_16x16x32_bf16(a1,b1,accS[1][1],0,0,0);
    }
    {
      float a63 = aL[63];
      #pragma unroll
      for (int i=0;i<2;i++){
        #pragma unroll
        for (int j=0;j<2;j++){
          int n = q0 + j*16 + ml;
          int pr = t0 + i*16 + r0;
          #pragma unroll
          for (int r=0;r<4;r++){
            int idx = (pr+r)*65 + n;
            Hf[idx] = Hf[idx]*a63 + accS[i][j][r];
          }
        }
      }
    }
    __syncthreads();                                  // B0: Hf + S reads done before next restage
  }
}

// ---------------- K8: gating + RMSNorm -> g (IN PLACE over z cols of zx) ----------------
__global__ void gate_kernel(unsigned short* __restrict__ zx,
                            const float* __restrict__ nw)
{
  int row = blockIdx.x; int tid = threadIdx.x;
  unsigned short* zr = zx + (size_t)row*ZLD;       // z cols [0,1536), y cols [1536,3072)
  float gv[6]; float s2 = 0.f;
  #pragma unroll
  for (int k=0;k<6;k++){
    int i = tid + k*256;
    float yv = bf2f(zr[1536 + i]);
    float zv = bf2f(zr[i]);
    float t = yv * siluf(zv);
    gv[k] = t; s2 += t*t;
  }
  for (int off=32; off>0; off>>=1) s2 += __shfl_down(s2, off);
  __shared__ float red[5];
  int wv = tid>>6;
  if ((tid&63)==0) red[wv] = s2;
  __syncthreads();
  if (tid==0) red[4] = red[0]+red[1]+red[2]+red[3];
  __syncthreads();
  float scale = rsqrtf(red[4]*(1.f/1536.f) + 1e-5f);
  #pragma unroll
  for (int k=0;k<6;k++){
    int i = tid + k*256;
    zr[i] = f2bf(gv[k]*scale*nw[i]);   // g overwrites z in place (each thread wrote only what it read)
  }
}

// ---------------- launch ----------------
extern "C" void kernel_launch(void* const* d_in, const int* in_sizes, int n_in,
                              void* d_out, int out_size, void* d_ws, size_t ws_size,
                              hipStream_t stream)
{
  (void)in_sizes; (void)n_in; (void)out_size; (void)ws_size;
  const float* x      = (const float*)d_in[0];
  const float* ln_w   = (const float*)d_in[1];
  const float* ln_b   = (const float*)d_in[2];
  const float* Win    = (const float*)d_in[3];
  const float* conv_w = (const float*)d_in[4];
  const float* conv_b = (const float*)d_in[5];
  const float* dt_bias= (const float*)d_in[6];
  const float* A_log  = (const float*)d_in[7];
  const float* D_skip = (const float*)d_in[8];
  const float* norm_w = (const float*)d_in[9];
  const float* Wout   = (const float*)d_in[10];
  float* out = (float*)d_out;
  char* ws = (char*)d_ws;

  // ws layout (total ~340 MB). S/hinit arrays eliminated by the fused scan.
  unsigned short* zx    = (unsigned short*)(ws + 0);            // 209,715,200  (z | xBC; y overlays xBC; g overlays z)
  unsigned short* xsT   = (unsigned short*)(ws + 209715200);    // 100,663,296  (xn overlaid: disjoint lifetime)
  unsigned short* xn    = xsT;                                  //  50,331,648  (dead after GEMM1, before conv writes xsT)
  unsigned short* winb  = (unsigned short*)(ws + 310378496);    //   4,952,064
  unsigned short* woutb = (unsigned short*)(ws + 315330560);    //   2,359,296
  float*          dtb   = (float*)        (ws + 317689856);     //   3,145,728
  float*          dtT   = (float*)        (ws + 320835584);     //   3,145,728
  float*          cum   = (float*)        (ws + 323981312);     //   3,145,728
  unsigned short* Bn    = (unsigned short*)(ws + 327127040);    //   4,194,304
  unsigned short* Cn    = (unsigned short*)(ws + 331321344);    //   4,194,304
  unsigned short* BT    = (unsigned short*)(ws + 335515648);    //   4,194,304  (end 339,709,952)

  cvt_kernel  <<<3570, 256, 0, stream>>>(Win, Wout, winb, woutb);
  ln_kernel   <<<BL, 256, 0, stream>>>(x, ln_w, ln_b, xn);
  gemm_kernel<1><<<256*26, 256, 0, stream>>>(xn, winb, 768, 768, DIPD, 26, zx, dtb, dt_bias, nullptr, nullptr);
  conv_kernel <<<dim3(26,64,8), 256, 0, stream>>>(zx, conv_w, conv_b, xsT, Bn, Cn, BT);
  cum_kernel  <<<3072, 256, 0, stream>>>(dtb, A_log, cum, dtT);
  fused_scan_kernel<<<DB*DH, 256, 0, stream>>>(Cn, Bn, xsT, BT, cum, dtT, D_skip, zx);
  gate_kernel <<<BL, 256, 0, stream>>>(zx, norm_w);
  gemm_kernel<2><<<256*6, 256, 0, stream>>>(zx, woutb, 1536, ZLD, DD, 6, nullptr, nullptr, nullptr, x, out);
}

// Round 10
// 907.886 us; speedup vs baseline: 1.0727x; 1.0028x over previous
//
#include <hip/hip_runtime.h>
#include <cstdint>

// Problem dims
#define DB   8
#define DL   4096
#define DD   768
#define DDI  1536
#define DN   64
#define DH   24
#define DP   64
#define DCD  1664
#define DIPD 3224
#define BL   (DB*DL)      // 32768 tokens
#define NCH  64           // chunks (L/64)
#define ZLD  3200         // zx row stride (z 1536 | xBC 1664)

typedef __attribute__((ext_vector_type(8))) short bf16x8;
typedef __attribute__((ext_vector_type(4))) float f32x4;

__device__ __forceinline__ unsigned short f2bf(float f){
  unsigned u = __float_as_uint(f);
  u += 0x7FFFu + ((u >> 16) & 1u);
  return (unsigned short)(u >> 16);
}
__device__ __forceinline__ float bf2f(unsigned short s){
  return __uint_as_float(((unsigned)s) << 16);
}
__device__ __forceinline__ unsigned pack2(unsigned short a, unsigned short b){
  return (unsigned)a | ((unsigned)b << 16);
}
__device__ __forceinline__ void pack16(const unsigned short* ov, uint4& u0, uint4& u1){
  u0.x = pack2(ov[0],ov[1]);  u0.y = pack2(ov[2],ov[3]);
  u0.z = pack2(ov[4],ov[5]);  u0.w = pack2(ov[6],ov[7]);
  u1.x = pack2(ov[8],ov[9]);  u1.y = pack2(ov[10],ov[11]);
  u1.z = pack2(ov[12],ov[13]); u1.w = pack2(ov[14],ov[15]);
}
__device__ __forceinline__ void async16(void* lds, const void* g){
  __builtin_amdgcn_global_load_lds((const __attribute__((address_space(1))) unsigned*)g,
                                   (__attribute__((address_space(3))) unsigned*)lds, 16, 0, 0);
}
__device__ __forceinline__ float softplusf(float v){
  return v > 15.f ? v : log1pf(expf(v));
}
__device__ __forceinline__ float siluf(float v){
  return v / (1.f + expf(-v));
}

// ---------------- K0: fp32 -> bf16 weight conversion (Win, Wout) ----------------
__global__ void cvt_kernel(const float* __restrict__ win, const float* __restrict__ wout,
                           unsigned short* __restrict__ winb, unsigned short* __restrict__ woutb){
  int i = blockIdx.x*256 + threadIdx.x;
  const int WN = (DIPD*DD)/4;   // 619008
  const int ON = (DD*DDI)/4;    // 294912
  if (i < WN){
    float4 v = ((const float4*)win)[i];
    uint2 o; o.x = pack2(f2bf(v.x), f2bf(v.y)); o.y = pack2(f2bf(v.z), f2bf(v.w));
    ((uint2*)winb)[i] = o;
  } else if (i < WN+ON){
    int j = i - WN;
    float4 v = ((const float4*)wout)[j];
    uint2 o; o.x = pack2(f2bf(v.x), f2bf(v.y)); o.y = pack2(f2bf(v.z), f2bf(v.w));
    ((uint2*)woutb)[j] = o;
  }
}

// ---------------- K1: LayerNorm -> xn (bf16) ----------------
__global__ void ln_kernel(const float* __restrict__ x, const float* __restrict__ w,
                          const float* __restrict__ bb, unsigned short* __restrict__ xn){
  int row = blockIdx.x; int tid = threadIdx.x;
  const float* xr = x + (size_t)row*DD;
  float v0=xr[tid], v1=xr[tid+256], v2=xr[tid+512];
  float s = v0+v1+v2;
  float s2 = v0*v0+v1*v1+v2*v2;
  for (int off=32; off>0; off>>=1){ s += __shfl_down(s, off); s2 += __shfl_down(s2, off); }
  __shared__ float red[10];
  int wv = tid>>6;
  if ((tid&63)==0){ red[wv]=s; red[4+wv]=s2; }
  __syncthreads();
  if (tid==0){
    float a=red[0]+red[1]+red[2]+red[3];
    float c=red[4]+red[5]+red[6]+red[7];
    red[8]=a*(1.f/768.f); red[9]=c*(1.f/768.f);
  }
  __syncthreads();
  float mu = red[8];
  float inv = rsqrtf(red[9]-mu*mu + 1e-5f);
  unsigned short* o = xn + (size_t)row*DD;
  o[tid]     = f2bf((v0-mu)*inv*w[tid]     + bb[tid]);
  o[tid+256] = f2bf((v1-mu)*inv*w[tid+256] + bb[tid+256]);
  o[tid+512] = f2bf((v2-mu)*inv*w[tid+512] + bb[tid+512]);
}

// ---------------- K2: bf16 MFMA GEMM (128x128, BK=32, dbuf, conflict-free swizzle) ----------------
// Settled structure (rounds 1-6): 2-phase latency-bound ceiling ~660 TF at this shape.
template<int MODE>
__launch_bounds__(256,4)
__global__ void gemm_kernel(const unsigned short* __restrict__ A,
                            const unsigned short* __restrict__ Bw,
                            int K, int lda, int Brows, int nbn,
                            unsigned short* __restrict__ zx, float* __restrict__ dtbuf,
                            const float* __restrict__ dt_bias,
                            const float* __restrict__ xres, float* __restrict__ outp)
{
  __shared__ __align__(16) unsigned short As[2*128*32];   // 16 KiB x2
  __shared__ __align__(16) unsigned short Bs[2*128*32];
  int tid = threadIdx.x; int lane = tid&63; int wv = tid>>6;
  int nwg  = gridDim.x;
  int orig = blockIdx.x;
  int q    = nwg >> 3;
  int wgid = (orig & 7)*q + (orig >> 3);
  int bm = wgid / nbn, bn = wgid % nbn;

  const int gc = ((lane&3) ^ ((lane>>3)&3)) * 8;
  const unsigned short* ap0 = A + (size_t)(bm*128 + wv*32 + (lane>>2))*lda + gc;
  const unsigned short* ap1 = ap0 + (size_t)16*lda;
  int rb0 = bn*128 + wv*32 + (lane>>2);      if (rb0 > Brows-1) rb0 = Brows-1;
  int rb1 = bn*128 + wv*32 + 16 + (lane>>2); if (rb1 > Brows-1) rb1 = Brows-1;
  const unsigned short* bp0 = Bw + (size_t)rb0*K + gc;
  const unsigned short* bp1 = Bw + (size_t)rb1*K + gc;
  unsigned short* la0 = &As[(wv*2)*512]; unsigned short* la1 = la0 + 512;
  unsigned short* lb0 = &Bs[(wv*2)*512]; unsigned short* lb1 = lb0 + 512;
  f32x4 acc[4][4];
  #pragma unroll
  for (int i=0;i<4;i++)
    #pragma unroll
    for (int j=0;j<4;j++) acc[i][j] = (f32x4){0.f,0.f,0.f,0.f};
  int mb = (wv&1)*64 + (lane&15);
  int nb = (wv>>1)*64 + (lane&15);
  const int cswz = ((lane>>4) ^ ((lane>>1)&3)) * 8;

  async16(la0, ap0); async16(la1, ap1);
  async16(lb0, bp0); async16(lb1, bp1);
  ap0 += 32; ap1 += 32; bp0 += 32; bp1 += 32;
  __syncthreads();

  int cur = 0;
  for (int k0=0; k0<K; k0+=32){
    if (k0 + 32 < K){
      int nxt = (cur^1)*4096;
      async16(la0 + nxt, ap0); async16(la1 + nxt, ap1);
      async16(lb0 + nxt, bp0); async16(lb1 + nxt, bp1);
      ap0 += 32; ap1 += 32; bp0 += 32; bp1 += 32;
    }
    const unsigned short* Ab = &As[cur*4096];
    const unsigned short* Bb = &Bs[cur*4096];
    bf16x8 af[4], bfr[4];
    #pragma unroll
    for (int i=0;i<4;i++) af[i]  = *(const bf16x8*)&Ab[(mb+i*16)*32 + cswz];
    #pragma unroll
    for (int j=0;j<4;j++) bfr[j] = *(const bf16x8*)&Bb[(nb+j*16)*32 + cswz];
    #pragma unroll
    for (int i=0;i<4;i++)
      #pragma unroll
      for (int j=0;j<4;j++)
        acc[i][j] = __builtin_amdgcn_mfma_f32_16x16x32_bf16(af[i], bfr[j], acc[i][j], 0, 0, 0);
    __syncthreads();
    cur ^= 1;
  }

  int mrow0 = bm*128 + (wv&1)*64 + (lane>>4)*4;
  int ncol0 = bn*128 + (wv>>1)*64 + (lane&15);
  #pragma unroll
  for (int i=0;i<4;i++){
    #pragma unroll
    for (int j=0;j<4;j++){
      int col = ncol0 + j*16;
      #pragma unroll
      for (int r=0;r<4;r++){
        int row = mrow0 + i*16 + r;
        float v = acc[i][j][r];
        if (MODE == 1){
          if (bn < 25){
            zx[(size_t)row*ZLD + col] = f2bf(v);
          } else {
            int cc = col - 3200;
            if (cc >= 0 && cc < DH) dtbuf[(size_t)row*DH + cc] = softplusf(v + dt_bias[cc]);
          }
        } else {
          float xr = __builtin_nontemporal_load(&xres[(size_t)row*DD + col]);
          __builtin_nontemporal_store(v + xr, &outp[(size_t)row*DD + col]);
        }
      }
    }
  }
}

// ---------------- K3: depthwise causal conv K=4 + bias + silu ----------------
__global__ void conv_kernel(const unsigned short* __restrict__ zx,
                            const float* __restrict__ cw, const float* __restrict__ cb,
                            unsigned short* __restrict__ xsT, unsigned short* __restrict__ Bn,
                            unsigned short* __restrict__ Cn, unsigned short* __restrict__ BT)
{
  int bx = blockIdx.x, by = blockIdx.y, b = blockIdx.z;
  int tid = threadIdx.x;
  __shared__ __align__(16) unsigned short in_s[67*64];
  int l0 = by*64;
  for (int idx = tid; idx < 67*8; idx += 256){
    int r = idx >> 3, c8 = idx & 7;
    int l = l0 - 3 + r;
    uint4 v = make_uint4(0u,0u,0u,0u);
    if (l >= 0) v = *(const uint4*)&zx[(size_t)(b*DL + l)*ZLD + 1536 + bx*64 + c8*8];
    *(uint4*)&in_s[r*64 + c8*8] = v;
  }
  __syncthreads();
  int c = tid & 63, li = tid >> 6;
  int chn = bx*64 + c;
  float w0=cw[chn*4+0], w1=cw[chn*4+1], w2=cw[chn*4+2], w3=cw[chn*4+3];
  float bias = cb[chn];
  unsigned short ov[16];
  #pragma unroll
  for (int q=0;q<16;q++){
    int t = li*16 + q;
    float a = bias
      + w0*bf2f(in_s[(t+0)*64 + c])
      + w1*bf2f(in_s[(t+1)*64 + c])
      + w2*bf2f(in_s[(t+2)*64 + c])
      + w3*bf2f(in_s[(t+3)*64 + c]);
    ov[q] = f2bf(siluf(a));
  }
  if (bx < 24){
    size_t base = ((((size_t)(b*DH + bx))*64 + by)*64 + c)*64 + li*16;
    uint4 u0,u1; pack16(ov,u0,u1);
    *(uint4*)&xsT[base]   = u0;
    *(uint4*)&xsT[base+8] = u1;
  } else if (bx == 24){
    #pragma unroll
    for (int q=0;q<16;q++)
      Bn[(size_t)(b*DL + l0 + li*16 + q)*64 + c] = ov[q];
    size_t bt = (((size_t)(b*64 + by))*64 + c)*64 + li*16;
    uint4 u0,u1; pack16(ov,u0,u1);
    *(uint4*)&BT[bt]   = u0;
    *(uint4*)&BT[bt+8] = u1;
  } else {
    #pragma unroll
    for (int q=0;q<16;q++)
      Cn[(size_t)(b*DL + l0 + li*16 + q)*64 + c] = ov[q];
  }
}

// ---------------- K4: per-(b,h,chunk) logdA cumsum (fp32) ----------------
__global__ void cum_kernel(const float* __restrict__ dt, const float* __restrict__ A_log,
                           float* __restrict__ cum, float* __restrict__ dtT)
{
  int tid = threadIdx.x; int lane = tid&63; int wv = tid>>6;
  int idx = blockIdx.x*4 + wv;            // (b*24+h)*64 + ch
  int b = idx / 1536; int r = idx % 1536; int h = r >> 6; int chk = r & 63;
  float dv = dt[((size_t)(b*DL + chk*64 + lane))*DH + h];
  float ld = -dv * expf(A_log[h]);
  for (int off=1; off<64; off<<=1){
    float v = __shfl_up(ld, off);
    if (lane >= off) ld += v;
  }
  size_t cb = (size_t)idx*64;
  cum[cb + lane] = ld;
  dtT[cb + lane] = dv;
}

// ---------------- K5: FUSED chunked scan, p-SPLIT (2 blocks per (b,h)) ----------------
// Round-10 delta vs round-9 (263us, MfmaUtil 3.9%, Occ 8.6%, 9860 cyc/chunk vs ~2000 busy):
// split the p dimension (64) into 2 halves -> 384 blocks. G/M depend only on C,B,cum and
// are duplicated (MFMA 4% busy, cheap); X-staging, Y, Xw, S, Hf all halve. Per-block LDS
// 64->46KB (2-3 blocks/CU allocable) -> a second block per CU overlaps the barrier stalls
// (m114 mechanism); per-wave Y-MFMA halves (16->8). T14 prefetch + padded Hf retained.
__global__ void fused_scan_kernel(const unsigned short* __restrict__ Cn,
                                  const unsigned short* __restrict__ Bn,
                                  const unsigned short* __restrict__ xsT,
                                  const unsigned short* __restrict__ BT,
                                  const float* __restrict__ cum, const float* __restrict__ dtT,
                                  const float* __restrict__ D_skip,
                                  unsigned short* __restrict__ yout)
{
  int idx0 = blockIdx.x; int ph = idx0 & 1; int bh = idx0 >> 1;
  int h = bh % DH; int b = bh / DH;
  int tid = threadIdx.x, lane = tid&63, wv = tid>>6;
  __shared__ __align__(16) unsigned short Ct[64*72];
  __shared__ __align__(16) unsigned short Bt[64*72];   // B(t,n) for G, then BT(n,t) for S
  __shared__ __align__(16) unsigned short Mt[64*72];   // M for Y1, then Xw (32 rows) for S
  __shared__ __align__(16) unsigned short Xt[32*72];   // X (p-half, t)
  __shared__ __align__(16) unsigned short Htb[32*72];  // bf16 h_prev (p-half, n)
  __shared__ float Hf[32*65];                          // fp32 running state (p-half, n)
  __shared__ float cumL[64], dtL[64], aL[64], wl[64];

  for (int i = tid; i < 32*65; i += 256) Hf[i] = 0.f;

  const int ml = lane&15, ko8 = (lane>>4)*8, r0 = (lane>>4)*4;
  const int t0 = (wv&1)*32, q0 = (wv>>1)*32;           // G/M wave layout (full 64x64)
  const int t0y = (wv&1)*32, p0y = (wv>>1)*16;         // Y wave layout (64t x 32p)
  const int p0s = (wv&1)*16, n0s = (wv>>1)*32;         // S wave layout (32p x 64n)
  const int rr = tid>>2,  cc  = (tid&3)*16;            // 64-row staging (2x uint4/thread)
  const int rr2 = tid>>3, cc2 = (tid&7)*8;             // 32-row staging (1x uint4/thread)
  const float dsk = D_skip[h];

  // ---- prologue: prefetch chunk 0 into registers ----
  uint4 rC0,rC1,rB0,rB1,rX0,rT0,rT1;
  float pcum = 0.f, pdt = 0.f;
  {
    size_t cb0 = ((size_t)((b*DH+h)*64 + 0))*64;
    size_t tb0 = cb0*64;
    size_t lrow0 = (size_t)(b*DL + rr);
    size_t btb0 = ((size_t)(b*64 + 0))*4096;
    rC0 = *(const uint4*)&Cn[lrow0*64 + cc];     rC1 = *(const uint4*)&Cn[lrow0*64 + cc + 8];
    rB0 = *(const uint4*)&Bn[lrow0*64 + cc];     rB1 = *(const uint4*)&Bn[lrow0*64 + cc + 8];
    rX0 = *(const uint4*)&xsT[tb0 + (ph*32 + rr2)*64 + cc2];
    rT0 = *(const uint4*)&BT[btb0 + rr*64 + cc]; rT1 = *(const uint4*)&BT[btb0 + rr*64 + cc + 8];
    if (tid < 64){ pcum = cum[cb0 + tid]; pdt = dtT[cb0 + tid]; }
  }
  __syncthreads();                                    // Hf zero visible

  for (int chk = 0; chk < NCH; ++chk){
    // ---- write prefetched regs to LDS ----
    *(uint4*)&Ct[rr*72 + cc]     = rC0;  *(uint4*)&Ct[rr*72 + cc + 8] = rC1;
    *(uint4*)&Bt[rr*72 + cc]     = rB0;  *(uint4*)&Bt[rr*72 + cc + 8] = rB1;
    *(uint4*)&Xt[rr2*72 + cc2]   = rX0;
    if (tid < 64){
      cumL[tid] = pcum; aL[tid] = expf(pcum); dtL[tid] = pdt;
    }
    __syncthreads();                                  // B1
    // hold current chunk's BT (needed mid-chunk) before prefetch overwrites
    uint4 curT0 = rT0, curT1 = rT1;
    // ---- T14: prefetch chunk k+1 (lands under this chunk's compute) ----
    if (chk + 1 < NCH){
      size_t cbn = ((size_t)((b*DH+h)*64 + (chk+1)))*64;
      size_t tbn = cbn*64;
      size_t lrown = (size_t)(b*DL + (chk+1)*64 + rr);
      size_t btbn = ((size_t)(b*64 + (chk+1)))*4096;
      rC0 = *(const uint4*)&Cn[lrown*64 + cc];     rC1 = *(const uint4*)&Cn[lrown*64 + cc + 8];
      rB0 = *(const uint4*)&Bn[lrown*64 + cc];     rB1 = *(const uint4*)&Bn[lrown*64 + cc + 8];
      rX0 = *(const uint4*)&xsT[tbn + (ph*32 + rr2)*64 + cc2];
      rT0 = *(const uint4*)&BT[btbn + rr*64 + cc]; rT1 = *(const uint4*)&BT[btbn + rr*64 + cc + 8];
      if (tid < 64){ pcum = cum[cbn + tid]; pdt = dtT[cbn + tid]; }
    }
    if (tid < 64) wl[tid] = expf(cumL[63] - cumL[tid]) * dtL[tid];
    // ---- Htb <- bf16(Hf) (h_prev snapshot, p-half rows) ----
    #pragma unroll
    for (int q=0;q<8;q++)
      Htb[rr2*72 + cc2 + q] = f2bf(Hf[rr2*65 + cc2 + q]);
    // ---- G = C @ B^T (full 64x64, duplicated across ph) ----
    f32x4 accG[2][2];
    #pragma unroll
    for (int i=0;i<2;i++)
      #pragma unroll
      for (int j=0;j<2;j++) accG[i][j] = (f32x4){0.f,0.f,0.f,0.f};
    #pragma unroll
    for (int kn=0; kn<64; kn+=32){
      bf16x8 a0 = *(const bf16x8*)&Ct[(t0+ml)*72    + kn + ko8];
      bf16x8 a1 = *(const bf16x8*)&Ct[(t0+16+ml)*72 + kn + ko8];
      bf16x8 b0 = *(const bf16x8*)&Bt[(q0+ml)*72    + kn + ko8];
      bf16x8 b1 = *(const bf16x8*)&Bt[(q0+16+ml)*72 + kn + ko8];
      accG[0][0] = __builtin_amdgcn_mfma_f32_16x16x32_bf16(a0,b0,accG[0][0],0,0,0);
      accG[0][1] = __builtin_amdgcn_mfma_f32_16x16x32_bf16(a0,b1,accG[0][1],0,0,0);
      accG[1][0] = __builtin_amdgcn_mfma_f32_16x16x32_bf16(a1,b0,accG[1][0],0,0,0);
      accG[1][1] = __builtin_amdgcn_mfma_f32_16x16x32_bf16(a1,b1,accG[1][1],0,0,0);
    }
    __syncthreads();                                  // B2 (G done: Bt free, Mt free)
    // ---- M[t][s] = (s<=t) ? G * exp(cum_t-cum_s) * dt_s : 0 ----
    #pragma unroll
    for (int i=0;i<2;i++){
      #pragma unroll
      for (int j=0;j<2;j++){
        int s = q0 + j*16 + ml;
        int tbs = t0 + i*16 + r0;
        #pragma unroll
        for (int r=0;r<4;r++){
          int t = tbs + r;
          float m = 0.f;
          if (s <= t) m = accG[i][j][r] * expf(cumL[t]-cumL[s]) * dtL[s];
          Mt[t*72 + s] = f2bf(m);
        }
      }
    }
    // ---- Ct <- a_t * Ct (in place, full rows) ----
    {
      float at = aL[rr];
      #pragma unroll
      for (int q=0;q<16;q++){
        int idx = rr*72 + cc + q;
        Ct[idx] = f2bf(bf2f(Ct[idx]) * at);
      }
    }
    // ---- restage Bt <- BT (n,t) from held registers ----
    *(uint4*)&Bt[rr*72 + cc]     = curT0;
    *(uint4*)&Bt[rr*72 + cc + 8] = curT1;
    __syncthreads();                                  // B3
    // ---- Y = M@X + (aC)@Htb (64t x 32p half) ; write y ----
    f32x4 accY[2];
    accY[0] = (f32x4){0.f,0.f,0.f,0.f};
    accY[1] = (f32x4){0.f,0.f,0.f,0.f};
    #pragma unroll
    for (int ks=0; ks<64; ks+=32){
      bf16x8 a0 = *(const bf16x8*)&Mt[(t0y+ml)*72    + ks + ko8];
      bf16x8 a1 = *(const bf16x8*)&Mt[(t0y+16+ml)*72 + ks + ko8];
      bf16x8 b0 = *(const bf16x8*)&Xt[(p0y+ml)*72    + ks + ko8];
      accY[0] = __builtin_amdgcn_mfma_f32_16x16x32_bf16(a0,b0,accY[0],0,0,0);
      accY[1] = __builtin_amdgcn_mfma_f32_16x16x32_bf16(a1,b0,accY[1],0,0,0);
    }
    #pragma unroll
    for (int kn=0; kn<64; kn+=32){
      bf16x8 a0 = *(const bf16x8*)&Ct[(t0y+ml)*72    + kn + ko8];
      bf16x8 a1 = *(const bf16x8*)&Ct[(t0y+16+ml)*72 + kn + ko8];
      bf16x8 b0 = *(const bf16x8*)&Htb[(p0y+ml)*72   + kn + ko8];
      accY[0] = __builtin_amdgcn_mfma_f32_16x16x32_bf16(a0,b0,accY[0],0,0,0);
      accY[1] = __builtin_amdgcn_mfma_f32_16x16x32_bf16(a1,b0,accY[1],0,0,0);
    }
    {
      int p = p0y + ml;                                // local p (0..31)
      int pg = ph*32 + p;                              // global p
      #pragma unroll
      for (int i=0;i<2;i++){
        int tbs = t0y + i*16 + r0;
        #pragma unroll
        for (int r=0;r<4;r++){
          int t = tbs + r;
          float xv = bf2f(Xt[p*72 + t]);
          float v = accY[i][r] + dsk*xv;
          yout[(size_t)(b*DL + chk*64 + t)*ZLD + 1536 + h*64 + pg] = f2bf(v);
        }
      }
    }
    __syncthreads();                                  // B4 (Y done: Mt, Xt, Htb free)
    // ---- Xw[p][t] = X[p][t] * wl[t] into Mt (32 rows) ----
    #pragma unroll
    for (int q=0;q<8;q++){
      int t = cc2 + q;
      Mt[rr2*72 + t] = f2bf(bf2f(Xt[rr2*72 + t]) * wl[t]);
    }
    __syncthreads();                                  // B5
    // ---- S = Xw @ BT^T (32p x 64n) ; Hf = a63*Hf + S ----
    f32x4 accS[2];
    accS[0] = (f32x4){0.f,0.f,0.f,0.f};
    accS[1] = (f32x4){0.f,0.f,0.f,0.f};
    #pragma unroll
    for (int ks=0; ks<64; ks+=32){
      bf16x8 a0 = *(const bf16x8*)&Mt[(p0s+ml)*72    + ks + ko8];
      bf16x8 b0 = *(const bf16x8*)&Bt[(n0s+ml)*72    + ks + ko8];
      bf16x8 b1 = *(const bf16x8*)&Bt[(n0s+16+ml)*72 + ks + ko8];
      accS[0] = __builtin_amdgcn_mfma_f32_16x16x32_bf16(a0,b0,accS[0],0,0,0);
      accS[1] = __builtin_amdgcn_mfma_f32_16x16x32_bf16(a0,b1,accS[1],0,0,0);
    }
    {
      float a63 = aL[63];
      #pragma unroll
      for (int j=0;j<2;j++){
        int n = n0s + j*16 + ml;
        #pragma unroll
        for (int r=0;r<4;r++){
          int idx = (p0s + r0 + r)*65 + n;
          Hf[idx] = Hf[idx]*a63 + accS[j][r];
        }
      }
    }
    __syncthreads();                                  // B0: Hf + S reads done before next restage
  }
}

// ---------------- K8: gating + RMSNorm -> g (IN PLACE over z cols of zx) ----------------
__global__ void gate_kernel(unsigned short* __restrict__ zx,
                            const float* __restrict__ nw)
{
  int row = blockIdx.x; int tid = threadIdx.x;
  unsigned short* zr = zx + (size_t)row*ZLD;       // z cols [0,1536), y cols [1536,3072)
  float gv[6]; float s2 = 0.f;
  #pragma unroll
  for (int k=0;k<6;k++){
    int i = tid + k*256;
    float yv = bf2f(zr[1536 + i]);
    float zv = bf2f(zr[i]);
    float t = yv * siluf(zv);
    gv[k] = t; s2 += t*t;
  }
  for (int off=32; off>0; off>>=1) s2 += __shfl_down(s2, off);
  __shared__ float red[5];
  int wv = tid>>6;
  if ((tid&63)==0) red[wv] = s2;
  __syncthreads();
  if (tid==0) red[4] = red[0]+red[1]+red[2]+red[3];
  __syncthreads();
  float scale = rsqrtf(red[4]*(1.f/1536.f) + 1e-5f);
  #pragma unroll
  for (int k=0;k<6;k++){
    int i = tid + k*256;
    zr[i] = f2bf(gv[k]*scale*nw[i]);   // g overwrites z in place (each thread wrote only what it read)
  }
}

// ---------------- launch ----------------
extern "C" void kernel_launch(void* const* d_in, const int* in_sizes, int n_in,
                              void* d_out, int out_size, void* d_ws, size_t ws_size,
                              hipStream_t stream)
{
  (void)in_sizes; (void)n_in; (void)out_size; (void)ws_size;
  const float* x      = (const float*)d_in[0];
  const float* ln_w   = (const float*)d_in[1];
  const float* ln_b   = (const float*)d_in[2];
  const float* Win    = (const float*)d_in[3];
  const float* conv_w = (const float*)d_in[4];
  const float* conv_b = (const float*)d_in[5];
  const float* dt_bias= (const float*)d_in[6];
  const float* A_log  = (const float*)d_in[7];
  const float* D_skip = (const float*)d_in[8];
  const float* norm_w = (const float*)d_in[9];
  const float* Wout   = (const float*)d_in[10];
  float* out = (float*)d_out;
  char* ws = (char*)d_ws;

  // ws layout (total ~340 MB). S/hinit arrays eliminated by the fused scan.
  unsigned short* zx    = (unsigned short*)(ws + 0);            // 209,715,200  (z | xBC; y overlays xBC; g overlays z)
  unsigned short* xsT   = (unsigned short*)(ws + 209715200);    // 100,663,296  (xn overlaid: disjoint lifetime)
  unsigned short* xn    = xsT;                                  //  50,331,648  (dead after GEMM1, before conv writes xsT)
  unsigned short* winb  = (unsigned short*)(ws + 310378496);    //   4,952,064
  unsigned short* woutb = (unsigned short*)(ws + 315330560);    //   2,359,296
  float*          dtb   = (float*)        (ws + 317689856);     //   3,145,728
  float*          dtT   = (float*)        (ws + 320835584);     //   3,145,728
  float*          cum   = (float*)        (ws + 323981312);     //   3,145,728
  unsigned short* Bn    = (unsigned short*)(ws + 327127040);    //   4,194,304
  unsigned short* Cn    = (unsigned short*)(ws + 331321344);    //   4,194,304
  unsigned short* BT    = (unsigned short*)(ws + 335515648);    //   4,194,304  (end 339,709,952)

  cvt_kernel  <<<3570, 256, 0, stream>>>(Win, Wout, winb, woutb);
  ln_kernel   <<<BL, 256, 0, stream>>>(x, ln_w, ln_b, xn);
  gemm_kernel<1><<<256*26, 256, 0, stream>>>(xn, winb, 768, 768, DIPD, 26, zx, dtb, dt_bias, nullptr, nullptr);
  conv_kernel <<<dim3(26,64,8), 256, 0, stream>>>(zx, conv_w, conv_b, xsT, Bn, Cn, BT);
  cum_kernel  <<<3072, 256, 0, stream>>>(dtb, A_log, cum, dtT);
  fused_scan_kernel<<<2*DB*DH, 256, 0, stream>>>(Cn, Bn, xsT, BT, cum, dtT, D_skip, zx);
  gate_kernel <<<BL, 256, 0, stream>>>(zx, norm_w);
  gemm_kernel<2><<<256*6, 256, 0, stream>>>(zx, woutb, 1536, ZLD, DD, 6, nullptr, nullptr, nullptr, x, out);
}

// Round 11
// 865.664 us; speedup vs baseline: 1.1250x; 1.0488x over previous
//
#include <hip/hip_runtime.h>
#include <cstdint>

// Problem dims
#define DB   8
#define DL   4096
#define DD   768
#define DDI  1536
#define DN   64
#define DH   24
#define DP   64
#define DCD  1664
#define DIPD 3224
#define BL   (DB*DL)      // 32768 tokens
#define NCH  64           // chunks (L/64)
#define ZLD  3200         // zx row stride (z 1536 | xBC 1664)

typedef __attribute__((ext_vector_type(8))) short bf16x8;
typedef __attribute__((ext_vector_type(4))) float f32x4;

__device__ __forceinline__ unsigned short f2bf(float f){
  unsigned u = __float_as_uint(f);
  u += 0x7FFFu + ((u >> 16) & 1u);
  return (unsigned short)(u >> 16);
}
__device__ __forceinline__ float bf2f(unsigned short s){
  return __uint_as_float(((unsigned)s) << 16);
}
__device__ __forceinline__ unsigned pack2(unsigned short a, unsigned short b){
  return (unsigned)a | ((unsigned)b << 16);
}
__device__ __forceinline__ void pack16(const unsigned short* ov, uint4& u0, uint4& u1){
  u0.x = pack2(ov[0],ov[1]);  u0.y = pack2(ov[2],ov[3]);
  u0.z = pack2(ov[4],ov[5]);  u0.w = pack2(ov[6],ov[7]);
  u1.x = pack2(ov[8],ov[9]);  u1.y = pack2(ov[10],ov[11]);
  u1.z = pack2(ov[12],ov[13]); u1.w = pack2(ov[14],ov[15]);
}
__device__ __forceinline__ void async16(void* lds, const void* g){
  __builtin_amdgcn_global_load_lds((const __attribute__((address_space(1))) unsigned*)g,
                                   (__attribute__((address_space(3))) unsigned*)lds, 16, 0, 0);
}
__device__ __forceinline__ float softplusf(float v){
  return v > 15.f ? v : log1pf(expf(v));
}
__device__ __forceinline__ float siluf(float v){
  return v / (1.f + expf(-v));
}

// ---------------- K0: fp32 -> bf16 weight conversion (Win, Wout) ----------------
__global__ void cvt_kernel(const float* __restrict__ win, const float* __restrict__ wout,
                           unsigned short* __restrict__ winb, unsigned short* __restrict__ woutb){
  int i = blockIdx.x*256 + threadIdx.x;
  const int WN = (DIPD*DD)/4;   // 619008
  const int ON = (DD*DDI)/4;    // 294912
  if (i < WN){
    float4 v = ((const float4*)win)[i];
    uint2 o; o.x = pack2(f2bf(v.x), f2bf(v.y)); o.y = pack2(f2bf(v.z), f2bf(v.w));
    ((uint2*)winb)[i] = o;
  } else if (i < WN+ON){
    int j = i - WN;
    float4 v = ((const float4*)wout)[j];
    uint2 o; o.x = pack2(f2bf(v.x), f2bf(v.y)); o.y = pack2(f2bf(v.z), f2bf(v.w));
    ((uint2*)woutb)[j] = o;
  }
}

// ---------------- K1: LayerNorm -> xn (bf16) ----------------
__global__ void ln_kernel(const float* __restrict__ x, const float* __restrict__ w,
                          const float* __restrict__ bb, unsigned short* __restrict__ xn){
  int row = blockIdx.x; int tid = threadIdx.x;
  const float* xr = x + (size_t)row*DD;
  float v0=xr[tid], v1=xr[tid+256], v2=xr[tid+512];
  float s = v0+v1+v2;
  float s2 = v0*v0+v1*v1+v2*v2;
  for (int off=32; off>0; off>>=1){ s += __shfl_down(s, off); s2 += __shfl_down(s2, off); }
  __shared__ float red[10];
  int wv = tid>>6;
  if ((tid&63)==0){ red[wv]=s; red[4+wv]=s2; }
  __syncthreads();
  if (tid==0){
    float a=red[0]+red[1]+red[2]+red[3];
    float c=red[4]+red[5]+red[6]+red[7];
    red[8]=a*(1.f/768.f); red[9]=c*(1.f/768.f);
  }
  __syncthreads();
  float mu = red[8];
  float inv = rsqrtf(red[9]-mu*mu + 1e-5f);
  unsigned short* o = xn + (size_t)row*DD;
  o[tid]     = f2bf((v0-mu)*inv*w[tid]     + bb[tid]);
  o[tid+256] = f2bf((v1-mu)*inv*w[tid+256] + bb[tid+256]);
  o[tid+512] = f2bf((v2-mu)*inv*w[tid+512] + bb[tid+512]);
}

// ---------------- K2: bf16 MFMA GEMM (128x128, BK=32) — T3 minimal 2-phase pipeline ----------------
// Session-best measured config (round 5: 861.07 us total). Double-buffered LDS + single
// barrier per K-iter; STAGE for tile t+1 issued into the OTHER buffer before compute of
// tile t; XCD-bijective remap (bn-fast) for A-panel L2 reuse; nontemporal MODE2 epilogue.
// Settled: six structural levers (8-phase port, occupancy floor, locality, bigger tile,
// dbuf timing, conflict-free swizzle) all measured null-or-regression vs this at rounds 1-6.
// MODE 1: zxbcdt = xn @ Win^T; cols [0,3200)->zx bf16 (stride ZLD), cols [3200,3224)->softplus(+dt_bias)->dt f32
// MODE 2: out = A(lda) @ Wout^T + x (fp32 store, nontemporal)
template<int MODE>
__launch_bounds__(256,4)
__global__ void gemm_kernel(const unsigned short* __restrict__ A,
                            const unsigned short* __restrict__ Bw,
                            int K, int lda, int Brows, int nbn,
                            unsigned short* __restrict__ zx, float* __restrict__ dtbuf,
                            const float* __restrict__ dt_bias,
                            const float* __restrict__ xres, float* __restrict__ outp)
{
  __shared__ __align__(16) unsigned short As[2*128*32];   // 16 KiB x2
  __shared__ __align__(16) unsigned short Bs[2*128*32];
  int tid = threadIdx.x; int lane = tid&63; int wv = tid>>6;
  // --- XCD-aware remap (nwg % 8 == 0 for both call sites), bn-fast for A-panel L2 reuse ---
  int nwg  = gridDim.x;
  int orig = blockIdx.x;
  int q    = nwg >> 3;
  int wgid = (orig & 7)*q + (orig >> 3);
  int bm = wgid / nbn, bn = wgid % nbn;

  const unsigned short* ap0 = A + (size_t)(bm*128 + wv*32 + (lane>>2))*lda + (lane&3)*8;
  const unsigned short* ap1 = ap0 + (size_t)16*lda;
  int rb0 = bn*128 + wv*32 + (lane>>2);      if (rb0 > Brows-1) rb0 = Brows-1;
  int rb1 = bn*128 + wv*32 + 16 + (lane>>2); if (rb1 > Brows-1) rb1 = Brows-1;
  const unsigned short* bp0 = Bw + (size_t)rb0*K + (lane&3)*8;
  const unsigned short* bp1 = Bw + (size_t)rb1*K + (lane&3)*8;
  unsigned short* la0 = &As[(wv*2)*512]; unsigned short* la1 = la0 + 512;
  unsigned short* lb0 = &Bs[(wv*2)*512]; unsigned short* lb1 = lb0 + 512;
  f32x4 acc[4][4];
  #pragma unroll
  for (int i=0;i<4;i++)
    #pragma unroll
    for (int j=0;j<4;j++) acc[i][j] = (f32x4){0.f,0.f,0.f,0.f};
  int mb = (wv&1)*64 + (lane&15);
  int nb = (wv>>1)*64 + (lane&15);
  int ko = (lane>>4)*8;

  // prologue: stage tile 0 into buffer 0, publish
  async16(la0, ap0); async16(la1, ap1);
  async16(lb0, bp0); async16(lb1, bp1);
  ap0 += 32; ap1 += 32; bp0 += 32; bp1 += 32;
  __syncthreads();

  int cur = 0;
  for (int k0=0; k0<K; k0+=32){
    // issue next tile's stage into the OTHER buffer (overlaps this iter's compute)
    if (k0 + 32 < K){
      int nxt = (cur^1)*4096;
      async16(la0 + nxt, ap0); async16(la1 + nxt, ap1);
      async16(lb0 + nxt, bp0); async16(lb1 + nxt, bp1);
      ap0 += 32; ap1 += 32; bp0 += 32; bp1 += 32;
    }
    const unsigned short* Ab = &As[cur*4096];
    const unsigned short* Bb = &Bs[cur*4096];
    bf16x8 af[4], bfr[4];
    #pragma unroll
    for (int i=0;i<4;i++) af[i]  = *(const bf16x8*)&Ab[(mb+i*16)*32 + ko];
    #pragma unroll
    for (int j=0;j<4;j++) bfr[j] = *(const bf16x8*)&Bb[(nb+j*16)*32 + ko];
    #pragma unroll
    for (int i=0;i<4;i++)
      #pragma unroll
      for (int j=0;j<4;j++)
        acc[i][j] = __builtin_amdgcn_mfma_f32_16x16x32_bf16(af[i], bfr[j], acc[i][j], 0, 0, 0);
    // single barrier per iter: drains vmcnt (next buffer staged) and guarantees all waves
    // finished reading buf[cur] before it is overwritten next iter.
    __syncthreads();
    cur ^= 1;
  }

  int mrow0 = bm*128 + (wv&1)*64 + (lane>>4)*4;
  int ncol0 = bn*128 + (wv>>1)*64 + (lane&15);
  #pragma unroll
  for (int i=0;i<4;i++){
    #pragma unroll
    for (int j=0;j<4;j++){
      int col = ncol0 + j*16;
      #pragma unroll
      for (int r=0;r<4;r++){
        int row = mrow0 + i*16 + r;
        float v = acc[i][j][r];
        if (MODE == 1){
          if (bn < 25){
            zx[(size_t)row*ZLD + col] = f2bf(v);
          } else {
            int cc = col - 3200;
            if (cc >= 0 && cc < DH) dtbuf[(size_t)row*DH + cc] = softplusf(v + dt_bias[cc]);
          }
        } else {
          float xr = __builtin_nontemporal_load(&xres[(size_t)row*DD + col]);
          __builtin_nontemporal_store(v + xr, &outp[(size_t)row*DD + col]);
        }
      }
    }
  }
}

// ---------------- K3: depthwise causal conv K=4 + bias + silu ----------------
// bx<24 -> xsT[b][h=bx][chunk][p][t]; bx==24 -> Bn (b,l,n) + BT (b,chunk,n,t); bx==25 -> Cn (b,l,n)
__global__ void conv_kernel(const unsigned short* __restrict__ zx,
                            const float* __restrict__ cw, const float* __restrict__ cb,
                            unsigned short* __restrict__ xsT, unsigned short* __restrict__ Bn,
                            unsigned short* __restrict__ Cn, unsigned short* __restrict__ BT)
{
  int bx = blockIdx.x, by = blockIdx.y, b = blockIdx.z;
  int tid = threadIdx.x;
  __shared__ __align__(16) unsigned short in_s[67*64];
  int l0 = by*64;
  for (int idx = tid; idx < 67*8; idx += 256){
    int r = idx >> 3, c8 = idx & 7;
    int l = l0 - 3 + r;
    uint4 v = make_uint4(0u,0u,0u,0u);
    if (l >= 0) v = *(const uint4*)&zx[(size_t)(b*DL + l)*ZLD + 1536 + bx*64 + c8*8];
    *(uint4*)&in_s[r*64 + c8*8] = v;
  }
  __syncthreads();
  int c = tid & 63, li = tid >> 6;
  int chn = bx*64 + c;
  float w0=cw[chn*4+0], w1=cw[chn*4+1], w2=cw[chn*4+2], w3=cw[chn*4+3];
  float bias = cb[chn];
  unsigned short ov[16];
  #pragma unroll
  for (int q=0;q<16;q++){
    int t = li*16 + q;
    float a = bias
      + w0*bf2f(in_s[(t+0)*64 + c])
      + w1*bf2f(in_s[(t+1)*64 + c])
      + w2*bf2f(in_s[(t+2)*64 + c])
      + w3*bf2f(in_s[(t+3)*64 + c]);
    ov[q] = f2bf(siluf(a));
  }
  if (bx < 24){
    size_t base = ((((size_t)(b*DH + bx))*64 + by)*64 + c)*64 + li*16;
    uint4 u0,u1; pack16(ov,u0,u1);
    *(uint4*)&xsT[base]   = u0;
    *(uint4*)&xsT[base+8] = u1;
  } else if (bx == 24){
    #pragma unroll
    for (int q=0;q<16;q++)
      Bn[(size_t)(b*DL + l0 + li*16 + q)*64 + c] = ov[q];
    size_t bt = (((size_t)(b*64 + by))*64 + c)*64 + li*16;
    uint4 u0,u1; pack16(ov,u0,u1);
    *(uint4*)&BT[bt]   = u0;
    *(uint4*)&BT[bt+8] = u1;
  } else {
    #pragma unroll
    for (int q=0;q<16;q++)
      Cn[(size_t)(b*DL + l0 + li*16 + q)*64 + c] = ov[q];
  }
}

// ---------------- K4: per-(b,h,chunk) logdA cumsum (fp32) ----------------
__global__ void cum_kernel(const float* __restrict__ dt, const float* __restrict__ A_log,
                           float* __restrict__ cum, float* __restrict__ dtT)
{
  int tid = threadIdx.x; int lane = tid&63; int wv = tid>>6;
  int idx = blockIdx.x*4 + wv;            // (b*24+h)*64 + ch
  int b = idx / 1536; int r = idx % 1536; int h = r >> 6; int chk = r & 63;
  float dv = dt[((size_t)(b*DL + chk*64 + lane))*DH + h];
  float ld = -dv * expf(A_log[h]);
  for (int off=1; off<64; off<<=1){
    float v = __shfl_up(ld, off);
    if (lane >= off) ld += v;
  }
  size_t cb = (size_t)idx*64;
  cum[cb + lane] = ld;
  dtT[cb + lane] = dv;
}

// ---------------- K5: phase A — per-chunk state contribution S = Xw^T @ B ----------------
__global__ void phaseA_kernel(const unsigned short* __restrict__ xsT,
                              const unsigned short* __restrict__ BT,
                              const float* __restrict__ cum, const float* __restrict__ dtT,
                              unsigned short* __restrict__ S)
{
  int chk = blockIdx.x, h = blockIdx.y, b = blockIdx.z;
  int tid = threadIdx.x, lane = tid&63, wv = tid>>6;
  __shared__ __align__(16) unsigned short Xw[64*72];
  __shared__ __align__(16) unsigned short Bl[64*72];
  __shared__ float wl[64];
  size_t cbase = ((size_t)((b*DH + h)*64 + chk))*64;
  if (tid < 64){
    float cv  = cum[cbase + tid];
    float c63 = cum[cbase + 63];
    wl[tid] = expf(c63 - cv) * dtT[cbase + tid];
  }
  __syncthreads();
  size_t xbase = cbase*64;
  size_t btb = ((size_t)(b*64 + chk))*4096;
  {
    int p = tid>>2, t16 = (tid&3)*16;
    #pragma unroll
    for (int half=0; half<2; half++){
      int t8 = t16 + half*8;
      uint4 xv = *(const uint4*)&xsT[xbase + p*64 + t8];
      const unsigned short* xp = (const unsigned short*)&xv;
      unsigned short ow[8];
      #pragma unroll
      for (int j=0;j<8;j++) ow[j] = f2bf(bf2f(xp[j]) * wl[t8+j]);
      uint4 u0; u0.x=pack2(ow[0],ow[1]); u0.y=pack2(ow[2],ow[3]); u0.z=pack2(ow[4],ow[5]); u0.w=pack2(ow[6],ow[7]);
      *(uint4*)&Xw[p*72 + t8] = u0;
      *(uint4*)&Bl[p*72 + t8] = *(const uint4*)&BT[btb + p*64 + t8];
    }
  }
  __syncthreads();
  int p0 = (wv&1)*32, n0 = (wv>>1)*32;
  int ml = lane&15, ko = (lane>>4)*8;
  f32x4 acc[2][2];
  #pragma unroll
  for (int i=0;i<2;i++)
    #pragma unroll
    for (int j=0;j<2;j++) acc[i][j] = (f32x4){0.f,0.f,0.f,0.f};
  #pragma unroll
  for (int ks=0; ks<64; ks+=32){
    bf16x8 a0 = *(const bf16x8*)&Xw[(p0+ml)*72    + ks + ko];
    bf16x8 a1 = *(const bf16x8*)&Xw[(p0+16+ml)*72 + ks + ko];
    bf16x8 b0 = *(const bf16x8*)&Bl[(n0+ml)*72    + ks + ko];
    bf16x8 b1 = *(const bf16x8*)&Bl[(n0+16+ml)*72 + ks + ko];
    acc[0][0] = __builtin_amdgcn_mfma_f32_16x16x32_bf16(a0,b0,acc[0][0],0,0,0);
    acc[0][1] = __builtin_amdgcn_mfma_f32_16x16x32_bf16(a0,b1,acc[0][1],0,0,0);
    acc[1][0] = __builtin_amdgcn_mfma_f32_16x16x32_bf16(a1,b0,acc[1][0],0,0,0);
    acc[1][1] = __builtin_amdgcn_mfma_f32_16x16x32_bf16(a1,b1,acc[1][1],0,0,0);
  }
  #pragma unroll
  for (int i=0;i<2;i++){
    #pragma unroll
    for (int j=0;j<2;j++){
      int n = n0 + j*16 + ml;
      int pr = p0 + i*16 + (lane>>4)*4;
      #pragma unroll
      for (int r=0;r<4;r++)
        S[xbase + (size_t)(pr+r)*64 + n] = f2bf(acc[i][j][r]);
    }
  }
}

// ---------------- K6: phase B — sequential cross-chunk state recurrence (IN PLACE: hinit==S) ----------------
// Depth-4 software pipeline: the chunk-(k) update consumes data loaded 4 iterations
// earlier (~4x iteration body >> L3 latency). Named registers only (rule #20).
__global__ void phaseB_kernel(unsigned short* __restrict__ S,   // becomes hinit
                              const float* __restrict__ cum)
{
  int bh = blockIdx.x; int tid = threadIdx.x;
  size_t base = (size_t)bh * (64*4096) + (size_t)tid*16;
  size_t cb = (size_t)bh * 4096;
  float st[16];
  #pragma unroll
  for (int q=0;q<16;q++) st[q] = 0.f;
  uint4 pa0 = *(const uint4*)&S[base];            uint4 pb0 = *(const uint4*)&S[base + 8];
  uint4 pa1 = *(const uint4*)&S[base + 4096];     uint4 pb1 = *(const uint4*)&S[base + 4096 + 8];
  uint4 pa2 = *(const uint4*)&S[base + 2*4096];   uint4 pb2 = *(const uint4*)&S[base + 2*4096 + 8];
  uint4 pa3 = *(const uint4*)&S[base + 3*4096];   uint4 pb3 = *(const uint4*)&S[base + 3*4096 + 8];
  for (int c4 = 0; c4 < 16; ++c4){
    size_t off = base + (size_t)c4*(4*4096);
#define PB_STEP(PA,PB,IDX)                                                       \
    {                                                                            \
      unsigned short ov[16];                                                     \
      _Pragma("unroll")                                                          \
      for (int q=0;q<16;q++) ov[q] = f2bf(st[q]);                                \
      uint4 u0,u1; pack16(ov,u0,u1);                                             \
      *(uint4*)&S[off + (IDX)*4096]     = u0;                                    \
      *(uint4*)&S[off + (IDX)*4096 + 8] = u1;                                    \
      float a = expf(cum[cb + (size_t)(c4*4 + (IDX))*64 + 63]);                  \
      const unsigned short* sp0 = (const unsigned short*)&PA;                    \
      const unsigned short* sp1 = (const unsigned short*)&PB;                    \
      _Pragma("unroll")                                                          \
      for (int q=0;q<8;q++) st[q]   = st[q]*a   + bf2f(sp0[q]);                  \
      _Pragma("unroll")                                                          \
      for (int q=0;q<8;q++) st[8+q] = st[8+q]*a + bf2f(sp1[q]);                  \
      if (c4 < 15){                                                              \
        PA = *(const uint4*)&S[off + ((IDX)+4)*4096];                            \
        PB = *(const uint4*)&S[off + ((IDX)+4)*4096 + 8];                        \
      }                                                                          \
    }
    PB_STEP(pa0,pb0,0)
    PB_STEP(pa1,pb1,1)
    PB_STEP(pa2,pb2,2)
    PB_STEP(pa3,pb3,3)
#undef PB_STEP
  }
}

// ---------------- K7: phase C — per-chunk outputs via MFMA ----------------
// writes y into zx's dead xBC columns: yout[(b*L+t)*ZLD + 1536 + h*64+p]
__global__ void phaseC_kernel(const unsigned short* __restrict__ Cn,
                              const unsigned short* __restrict__ Bn,
                              const unsigned short* __restrict__ xsT,
                              const unsigned short* __restrict__ hinit,
                              const float* __restrict__ cum, const float* __restrict__ dtT,
                              const float* __restrict__ D_skip,
                              unsigned short* __restrict__ yout)
{
  int h = blockIdx.x, chk = blockIdx.y, b = blockIdx.z;
  int tid = threadIdx.x, lane = tid&63, wv = tid>>6;
  __shared__ __align__(16) unsigned short Ct[64*72];
  __shared__ __align__(16) unsigned short Bt[64*72];
  __shared__ __align__(16) unsigned short Xt[64*72];
  __shared__ __align__(16) unsigned short Ht[64*72];
  __shared__ __align__(16) unsigned short Mt[64*72];
  __shared__ float cumL[64], dtL[64], aL[64];
  int l0 = chk*64;
  size_t cb = ((size_t)((b*DH+h)*64 + chk))*64;
  size_t tb = cb*64;
  {
    int r = tid>>2, c16 = (tid&3)*16;
    size_t lrow = (size_t)(b*DL + l0 + r);
    #pragma unroll
    for (int half=0; half<2; half++){
      int c8 = c16 + half*8;
      *(uint4*)&Ct[r*72 + c8] = *(const uint4*)&Cn[lrow*64 + c8];
      *(uint4*)&Bt[r*72 + c8] = *(const uint4*)&Bn[lrow*64 + c8];
      *(uint4*)&Xt[r*72 + c8] = *(const uint4*)&xsT[tb + r*64 + c8];
      *(uint4*)&Ht[r*72 + c8] = *(const uint4*)&hinit[tb + r*64 + c8];
    }
  }
  if (tid < 64){
    float cv = cum[cb + tid];
    cumL[tid] = cv; aL[tid] = expf(cv); dtL[tid] = dtT[cb + tid];
  }
  __syncthreads();
  int ml = lane&15, ko8 = (lane>>4)*8, r0 = (lane>>4)*4;
  int t0 = (wv&1)*32, q0 = (wv>>1)*32;   // q0 = s-quadrant for G, p-quadrant for Y
  f32x4 accG[2][2];
  #pragma unroll
  for (int i=0;i<2;i++)
    #pragma unroll
    for (int j=0;j<2;j++) accG[i][j] = (f32x4){0.f,0.f,0.f,0.f};
  #pragma unroll
  for (int kn=0; kn<64; kn+=32){
    bf16x8 a0 = *(const bf16x8*)&Ct[(t0+ml)*72    + kn + ko8];
    bf16x8 a1 = *(const bf16x8*)&Ct[(t0+16+ml)*72 + kn + ko8];
    bf16x8 b0 = *(const bf16x8*)&Bt[(q0+ml)*72    + kn + ko8];
    bf16x8 b1 = *(const bf16x8*)&Bt[(q0+16+ml)*72 + kn + ko8];
    accG[0][0] = __builtin_amdgcn_mfma_f32_16x16x32_bf16(a0,b0,accG[0][0],0,0,0);
    accG[0][1] = __builtin_amdgcn_mfma_f32_16x16x32_bf16(a0,b1,accG[0][1],0,0,0);
    accG[1][0] = __builtin_amdgcn_mfma_f32_16x16x32_bf16(a1,b0,accG[1][0],0,0,0);
    accG[1][1] = __builtin_amdgcn_mfma_f32_16x16x32_bf16(a1,b1,accG[1][1],0,0,0);
  }
  __syncthreads();
  // M[t][s] = (s<=t) ? G * exp(cum_t - cum_s) * dt_s : 0
  #pragma unroll
  for (int i=0;i<2;i++){
    #pragma unroll
    for (int j=0;j<2;j++){
      int s = q0 + j*16 + ml;
      int tbs = t0 + i*16 + r0;
      #pragma unroll
      for (int r=0;r<4;r++){
        int t = tbs + r;
        float m = 0.f;
        if (s <= t) m = accG[i][j][r] * expf(cumL[t]-cumL[s]) * dtL[s];
        Mt[t*72 + s] = f2bf(m);
      }
    }
  }
  // Ct <- a_t * Ct (in place, post-G)
  {
    int rr = tid>>2; int cc = (tid&3)*16;
    float at = aL[rr];
    #pragma unroll
    for (int q=0;q<16;q++){
      int idx = rr*72 + cc + q;
      Ct[idx] = f2bf(bf2f(Ct[idx]) * at);
    }
  }
  __syncthreads();
  f32x4 accY[2][2];
  #pragma unroll
  for (int i=0;i<2;i++)
    #pragma unroll
    for (int j=0;j<2;j++) accY[i][j] = (f32x4){0.f,0.f,0.f,0.f};
  #pragma unroll
  for (int ks=0; ks<64; ks+=32){
    bf16x8 a0 = *(const bf16x8*)&Mt[(t0+ml)*72    + ks + ko8];
    bf16x8 a1 = *(const bf16x8*)&Mt[(t0+16+ml)*72 + ks + ko8];
    bf16x8 b0 = *(const bf16x8*)&Xt[(q0+ml)*72    + ks + ko8];
    bf16x8 b1 = *(const bf16x8*)&Xt[(q0+16+ml)*72 + ks + ko8];
    accY[0][0] = __builtin_amdgcn_mfma_f32_16x16x32_bf16(a0,b0,accY[0][0],0,0,0);
    accY[0][1] = __builtin_amdgcn_mfma_f32_16x16x32_bf16(a0,b1,accY[0][1],0,0,0);
    accY[1][0] = __builtin_amdgcn_mfma_f32_16x16x32_bf16(a1,b0,accY[1][0],0,0,0);
    accY[1][1] = __builtin_amdgcn_mfma_f32_16x16x32_bf16(a1,b1,accY[1][1],0,0,0);
  }
  #pragma unroll
  for (int kn=0; kn<64; kn+=32){
    bf16x8 a0 = *(const bf16x8*)&Ct[(t0+ml)*72    + kn + ko8];
    bf16x8 a1 = *(const bf16x8*)&Ct[(t0+16+ml)*72 + kn + ko8];
    bf16x8 b0 = *(const bf16x8*)&Ht[(q0+ml)*72    + kn + ko8];
    bf16x8 b1 = *(const bf16x8*)&Ht[(q0+16+ml)*72 + kn + ko8];
    accY[0][0] = __builtin_amdgcn_mfma_f32_16x16x32_bf16(a0,b0,accY[0][0],0,0,0);
    accY[0][1] = __builtin_amdgcn_mfma_f32_16x16x32_bf16(a0,b1,accY[0][1],0,0,0);
    accY[1][0] = __builtin_amdgcn_mfma_f32_16x16x32_bf16(a1,b0,accY[1][0],0,0,0);
    accY[1][1] = __builtin_amdgcn_mfma_f32_16x16x32_bf16(a1,b1,accY[1][1],0,0,0);
  }
  float dsk = D_skip[h];
  #pragma unroll
  for (int i=0;i<2;i++){
    #pragma unroll
    for (int j=0;j<2;j++){
      int p = q0 + j*16 + ml;
      int tbs = t0 + i*16 + r0;
      #pragma unroll
      for (int r=0;r<4;r++){
        int t = tbs + r;
        float xv = bf2f(Xt[p*72 + t]);
        float v = accY[i][j][r] + dsk*xv;
        yout[(size_t)(b*DL + l0 + t)*ZLD + 1536 + h*64 + p] = f2bf(v);
      }
    }
  }
}

// ---------------- K8: gating + RMSNorm -> g (IN PLACE over z cols of zx) ----------------
__global__ void gate_kernel(unsigned short* __restrict__ zx,
                            const float* __restrict__ nw)
{
  int row = blockIdx.x; int tid = threadIdx.x;
  unsigned short* zr = zx + (size_t)row*ZLD;       // z cols [0,1536), y cols [1536,3072)
  float gv[6]; float s2 = 0.f;
  #pragma unroll
  for (int k=0;k<6;k++){
    int i = tid + k*256;
    float yv = bf2f(zr[1536 + i]);
    float zv = bf2f(zr[i]);
    float t = yv * siluf(zv);
    gv[k] = t; s2 += t*t;
  }
  for (int off=32; off>0; off>>=1) s2 += __shfl_down(s2, off);
  __shared__ float red[5];
  int wv = tid>>6;
  if ((tid&63)==0) red[wv] = s2;
  __syncthreads();
  if (tid==0) red[4] = red[0]+red[1]+red[2]+red[3];
  __syncthreads();
  float scale = rsqrtf(red[4]*(1.f/1536.f) + 1e-5f);
  #pragma unroll
  for (int k=0;k<6;k++){
    int i = tid + k*256;
    zr[i] = f2bf(gv[k]*scale*nw[i]);   // g overwrites z in place (each thread wrote only what it read)
  }
}

// ---------------- launch ----------------
extern "C" void kernel_launch(void* const* d_in, const int* in_sizes, int n_in,
                              void* d_out, int out_size, void* d_ws, size_t ws_size,
                              hipStream_t stream)
{
  (void)in_sizes; (void)n_in; (void)out_size; (void)ws_size;
  const float* x      = (const float*)d_in[0];
  const float* ln_w   = (const float*)d_in[1];
  const float* ln_b   = (const float*)d_in[2];
  const float* Win    = (const float*)d_in[3];
  const float* conv_w = (const float*)d_in[4];
  const float* conv_b = (const float*)d_in[5];
  const float* dt_bias= (const float*)d_in[6];
  const float* A_log  = (const float*)d_in[7];
  const float* D_skip = (const float*)d_in[8];
  const float* norm_w = (const float*)d_in[9];
  const float* Wout   = (const float*)d_in[10];
  float* out = (float*)d_out;
  char* ws = (char*)d_ws;

  // ws layout (total ~340 MB). S/hinit (100.66 MB) lives in d_out (dead until GEMM2).
  unsigned short* zx    = (unsigned short*)(ws + 0);            // 209,715,200  (z | xBC; y overlays xBC; g overlays z)
  unsigned short* xsT   = (unsigned short*)(ws + 209715200);    // 100,663,296  (xn overlaid: disjoint lifetime)
  unsigned short* xn    = xsT;                                  //  50,331,648  (dead after GEMM1, before conv writes xsT)
  unsigned short* winb  = (unsigned short*)(ws + 310378496);    //   4,952,064
  unsigned short* woutb = (unsigned short*)(ws + 315330560);    //   2,359,296
  float*          dtb   = (float*)        (ws + 317689856);     //   3,145,728
  float*          dtT   = (float*)        (ws + 320835584);     //   3,145,728
  float*          cum   = (float*)        (ws + 323981312);     //   3,145,728
  unsigned short* Bn    = (unsigned short*)(ws + 327127040);    //   4,194,304
  unsigned short* Cn    = (unsigned short*)(ws + 331321344);    //   4,194,304
  unsigned short* BT    = (unsigned short*)(ws + 335515648);    //   4,194,304  (end 339,709,952)
  unsigned short* S     = (unsigned short*)d_out;               // 100,663,296 == out_size*4 exactly

  cvt_kernel  <<<3570, 256, 0, stream>>>(Win, Wout, winb, woutb);
  ln_kernel   <<<BL, 256, 0, stream>>>(x, ln_w, ln_b, xn);
  gemm_kernel<1><<<256*26, 256, 0, stream>>>(xn, winb, 768, 768, DIPD, 26, zx, dtb, dt_bias, nullptr, nullptr);
  conv_kernel <<<dim3(26,64,8), 256, 0, stream>>>(zx, conv_w, conv_b, xsT, Bn, Cn, BT);
  cum_kernel  <<<3072, 256, 0, stream>>>(dtb, A_log, cum, dtT);
  phaseA_kernel<<<dim3(64,24,8), 256, 0, stream>>>(xsT, BT, cum, dtT, S);
  phaseB_kernel<<<192, 256, 0, stream>>>(S, cum);
  phaseC_kernel<<<dim3(24,64,8), 256, 0, stream>>>(Cn, Bn, xsT, S, cum, dtT, D_skip, zx);
  gate_kernel <<<BL, 256, 0, stream>>>(zx, norm_w);
  gemm_kernel<2><<<256*6, 256, 0, stream>>>(zx, woutb, 1536, ZLD, DD, 6, nullptr, nullptr, nullptr, x, out);
}